// Round 15
// baseline (143.423 us; speedup 1.0000x reference)
//
#include <hip/hip_runtime.h>
#include <math.h>

// ---------------------------------------------------------------------------
// MultiHeadAttention forward, MI355X/gfx950.  Round 15.
//   pack3/pack4: fp32 -> bf16 (frozen)
//   gemm_qkv / gemm_out: R13-exact (T2-swizzled LDS)
//   attn_fwd: KV-SPLIT for occupancy: grid 1024 = (bh 32)x(qtile 16)x(kvhalf 2),
//     8 waves x 16 q-rows, each block does 1024 kv in 16 single-buffered
//     64-kv tiles (LDS 32KB, VGPR<=64 via launch_bounds(512,8)) -> 4 blocks/CU
//     = 32 waves/CU (was 16).  Inner loop math R9-exact.  Partials (bf16 acc,
//     fp32 m/l) land in dead xq/xk/xv workspace.
//   attn_combine: log-sum-exp merge of the two halves -> opb (HBM-bound ~5us)
// ---------------------------------------------------------------------------

typedef __attribute__((ext_vector_type(8))) short short8;     // 8 x bf16 frag
typedef __attribute__((ext_vector_type(4))) float f32x4;      // MFMA acc
typedef __attribute__((ext_vector_type(4))) float float4v;
typedef __attribute__((ext_vector_type(4))) unsigned short ushort4v;
typedef __attribute__((ext_vector_type(2))) unsigned int uint2v;

typedef __attribute__((address_space(3))) unsigned int lds_uint;
typedef __attribute__((address_space(1))) unsigned int glb_uint;

__device__ __forceinline__ void gload_lds16(const void* g, void* l) {
    __builtin_amdgcn_global_load_lds((glb_uint*)(unsigned long long)g,
                                     (lds_uint*)(unsigned int)(unsigned long long)l,
                                     16, 0, 0);
}

__device__ __forceinline__ unsigned short f32_bf16(float f) {
    union { float f; unsigned int u; } x; x.f = f;
    unsigned int r = x.u + 0x7fffu + ((x.u >> 16) & 1u);   // RNE
    return (unsigned short)(r >> 16);
}

__device__ __forceinline__ float bf16_f32(unsigned short u) {
    union { unsigned int i; float f; } x; x.i = ((unsigned int)u) << 16;
    return x.f;
}

__device__ __forceinline__ unsigned int cvt_pk_bf16(float lo, float hi) {
    unsigned int r;
    asm("v_cvt_pk_bf16_f32 %0, %1, %2" : "=v"(r) : "v"(lo), "v"(hi));
    return r;
}

// single-instruction exp2
__device__ __forceinline__ float exp2_fast(float x) {
    float r;
    asm("v_exp_f32 %0, %1" : "=v"(r) : "v"(x));
    return r;
}

// SCALE * log2(e): folded into Q projection so softmax runs in exp2 domain
#define QSCALE 0.18033688011112042f

// ---------------------------------------------------------------------------
__global__ void pack3_bf16(const float* __restrict__ a, const float* __restrict__ b,
                           const float* __restrict__ c,
                           unsigned short* __restrict__ oa, unsigned short* __restrict__ ob,
                           unsigned short* __restrict__ oc, int n4) {
    const int y = blockIdx.y;
    const float* in = (y == 0) ? a : (y == 1) ? b : c;
    unsigned short* out = (y == 0) ? oa : (y == 1) ? ob : oc;
    int i = blockIdx.x * blockDim.x + threadIdx.x;
    if (i < n4) {
        float4v v = ((const float4v*)in)[i];
        ushort4v o;
        o.x = f32_bf16(v.x); o.y = f32_bf16(v.y);
        o.z = f32_bf16(v.z); o.w = f32_bf16(v.w);
        ((ushort4v*)out)[i] = o;
    }
}

__global__ void pack4_bf16(const float* __restrict__ a, const float* __restrict__ b,
                           const float* __restrict__ c, const float* __restrict__ d,
                           unsigned short* __restrict__ oa, unsigned short* __restrict__ ob,
                           unsigned short* __restrict__ oc, unsigned short* __restrict__ od,
                           int n4) {
    const int y = blockIdx.y;
    const float* in = (y == 0) ? a : (y == 1) ? b : (y == 2) ? c : d;
    unsigned short* out = (y == 0) ? oa : (y == 1) ? ob : (y == 2) ? oc : od;
    int i = blockIdx.x * blockDim.x + threadIdx.x;
    if (i < n4) {
        float4v v = ((const float4v*)in)[i];
        ushort4v o;
        o.x = f32_bf16(v.x); o.y = f32_bf16(v.y);
        o.z = f32_bf16(v.z); o.w = f32_bf16(v.w);
        ((ushort4v*)out)[i] = o;
    }
}

// ---------------------------------------------------------------------------
// Batched QKV projection GEMM (R13-exact: 4 waves + T2 XOR-swizzled LDS).
__global__ __launch_bounds__(256, 2) void gemm_qkv(
    const unsigned short* __restrict__ A0, const unsigned short* __restrict__ A1,
    const unsigned short* __restrict__ A2,
    const unsigned short* __restrict__ W0, const unsigned short* __restrict__ W1,
    const unsigned short* __restrict__ W2,
    const float* __restrict__ bs0, const float* __restrict__ bs1,
    const float* __restrict__ bs2,
    unsigned short* __restrict__ O0, unsigned short* __restrict__ O1,
    unsigned short* __restrict__ O2)
{
    const int z = blockIdx.z;
    const unsigned short* A = (z == 0) ? A0 : (z == 1) ? A1 : A2;
    const unsigned short* W = (z == 0) ? W0 : (z == 1) ? W1 : W2;
    const float* bias        = (z == 0) ? bs0 : (z == 1) ? bs1 : bs2;
    unsigned short* C        = (z == 0) ? O0 : (z == 1) ? O1 : O2;
    const float oscale = (z == 0) ? QSCALE : 1.0f;
    const int N = 1024, K = 1024;

    __shared__ unsigned short As[128 * 64];
    __shared__ unsigned short Bs[128 * 64];
    const int tid  = threadIdx.x;
    const int lane = tid & 63, wave = tid >> 6;
    const int l15 = lane & 15, l4 = lane >> 4;
    const int bm = blockIdx.y * 128, bn = blockIdx.x * 128;
    const int wr = wave >> 1, wc = wave & 1;
    const int swz = l15 & 7;                    // XOR key (8-short units)

    f32x4 acc[4][4];
    #pragma unroll
    for (int i = 0; i < 4; ++i)
        #pragma unroll
        for (int j = 0; j < 4; ++j)
            #pragma unroll
            for (int e = 0; e < 4; ++e) acc[i][j][e] = 0.f;

    const int srow = lane >> 3;                 // row 0..7 within chunk
    const int scol = ((lane & 7) ^ srow) * 8;   // pre-swizzled source col

    for (int k0 = 0; k0 < K; k0 += 64) {
        __syncthreads();
        #pragma unroll
        for (int i = 0; i < 4; ++i) {
            int c = wave * 4 + i;
            int row = c * 8 + srow;
            gload_lds16(A + (size_t)(bm + row) * K + k0 + scol, &As[c * 512]);
            gload_lds16(W + (size_t)(bn + row) * K + k0 + scol, &Bs[c * 512]);
        }
        __syncthreads();
        #pragma unroll
        for (int kk = 0; kk < 2; ++kk) {
            short8 af[4], bf[4];
            const int ko = ((kk * 4 + l4) ^ swz) << 3;   // swizzled col
            #pragma unroll
            for (int i = 0; i < 4; ++i)
                af[i] = *(const short8*)&As[(wr * 64 + i * 16 + l15) * 64 + ko];
            #pragma unroll
            for (int j = 0; j < 4; ++j)
                bf[j] = *(const short8*)&Bs[(wc * 64 + j * 16 + l15) * 64 + ko];
            #pragma unroll
            for (int i = 0; i < 4; ++i)
                #pragma unroll
                for (int j = 0; j < 4; ++j)
                    acc[i][j] = __builtin_amdgcn_mfma_f32_16x16x32_bf16(
                        af[i], bf[j], acc[i][j], 0, 0, 0);
        }
    }

    #pragma unroll
    for (int j = 0; j < 4; ++j) {
        const int col = bn + wc * 64 + j * 16 + l15;
        const float bj = bias[col];
        #pragma unroll
        for (int i = 0; i < 4; ++i) {
            const int row0 = bm + wr * 64 + i * 16 + l4 * 4;
            #pragma unroll
            for (int r = 0; r < 4; ++r) {
                const int row = row0 + r;
                const float v = (acc[i][j][r] + bj) * oscale;
                if (z < 2) {
                    C[(size_t)row * N + col] = f32_bf16(v);
                } else {
                    const int b = row >> 11, t = row & 2047;
                    C[(((size_t)((b << 4) + (col >> 6)) * 64
                        + (col & 63)) << 11) + t] = f32_bf16(v);
                }
            }
        }
    }
}

// ---------------------------------------------------------------------------
// Output-projection GEMM (fp32 out).  R13-exact: 64x128 dbuf + T2 swizzle.
__global__ __launch_bounds__(256, 3) void gemm_out(
    const unsigned short* __restrict__ A,
    const unsigned short* __restrict__ W,
    const float* __restrict__ bias,
    float* __restrict__ C)
{
    const int N = 1024, K = 1024;
    __shared__ unsigned short As[2][64 * 64];
    __shared__ unsigned short Bs[2][128 * 64];
    const int tid  = threadIdx.x;
    const int lane = tid & 63, wave = tid >> 6;
    const int l15 = lane & 15, l4 = lane >> 4;
    const int bm = blockIdx.y * 64, bn = blockIdx.x * 128;
    const int wr = wave >> 1, wc = wave & 1;
    const int swz = l15 & 7;

    f32x4 acc[2][4];
    #pragma unroll
    for (int i = 0; i < 2; ++i)
        #pragma unroll
        for (int j = 0; j < 4; ++j)
            #pragma unroll
            for (int e = 0; e < 4; ++e) acc[i][j][e] = 0.f;

    const int srow = lane >> 3;
    const int scol = ((lane & 7) ^ srow) * 8;

    auto stage = [&](int bf, int k0) {
        #pragma unroll
        for (int i = 0; i < 2; ++i) {
            const int c = wave * 2 + i;
            gload_lds16(A + (size_t)(bm + c * 8 + srow) * K + k0 + scol,
                        &As[bf][c * 512]);
        }
        #pragma unroll
        for (int i = 0; i < 4; ++i) {
            const int c = wave * 4 + i;
            gload_lds16(W + (size_t)(bn + c * 8 + srow) * K + k0 + scol,
                        &Bs[bf][c * 512]);
        }
    };

    stage(0, 0);
    __syncthreads();

    int bufi = 0;
    for (int k0 = 0; k0 < K; k0 += 64) {
        if (k0 + 64 < K) stage(bufi ^ 1, k0 + 64);
        #pragma unroll
        for (int kk = 0; kk < 2; ++kk) {
            short8 af[2], bf[4];
            const int ko = ((kk * 4 + l4) ^ swz) << 3;
            #pragma unroll
            for (int i = 0; i < 2; ++i)
                af[i] = *(const short8*)&As[bufi][(wr * 32 + i * 16 + l15) * 64 + ko];
            #pragma unroll
            for (int j = 0; j < 4; ++j)
                bf[j] = *(const short8*)&Bs[bufi][(wc * 64 + j * 16 + l15) * 64 + ko];
            #pragma unroll
            for (int i = 0; i < 2; ++i)
                #pragma unroll
                for (int j = 0; j < 4; ++j)
                    acc[i][j] = __builtin_amdgcn_mfma_f32_16x16x32_bf16(
                        af[i], bf[j], acc[i][j], 0, 0, 0);
        }
        __syncthreads();
        bufi ^= 1;
    }

    #pragma unroll
    for (int j = 0; j < 4; ++j) {
        const int col = bn + wc * 64 + j * 16 + l15;
        const float bj = bias[col];
        #pragma unroll
        for (int i = 0; i < 2; ++i) {
            const int row0 = bm + wr * 32 + i * 16 + l4 * 4;
            #pragma unroll
            for (int r = 0; r < 4; ++r)
                C[(size_t)(row0 + r) * N + col] = acc[i][j][r] + bj;
        }
    }
}

// ---------------------------------------------------------------------------
// Flash attention, R15 kv-split.  grid 1024 = (bh 32)x(qtile 16)x(kvhalf 2),
// 8 waves x 16 q-rows, 1024 kv per block in 16 single-buffered 64-kv tiles.
// LDS 32KB, launch_bounds(512,8) (VGPR cap 64) -> 4 blocks/CU = 32 waves/CU.
// Inner-loop math = R9-exact.  Writes UNNORMALIZED bf16 acc + fp32 (m,l).
__global__ __launch_bounds__(512, 8) void attn_fwd(
    const unsigned short* __restrict__ qp,
    const unsigned short* __restrict__ kp,
    const unsigned short* __restrict__ vt,
    unsigned short* __restrict__ pacc,   // [2][65536][64] bf16
    float* __restrict__ pml)             // [2][65536][2]  {m, l}
{
    __shared__ unsigned short Ks[64 * 64];      // [kv][d]  swizzled
    __shared__ unsigned short Vs[64 * 64];      // [d][kv]  swizzled
    __shared__ unsigned short P[8][16 * 64];    // [wave][q][kv] swizzled

    const int tid = threadIdx.x;
    const int lane = tid & 63, wave = tid >> 6;  // wave 0..7
    const int l15 = lane & 15, l4 = lane >> 4;
    const int swz = (l15 & 7) << 3;             // XOR mask in short units

    // XCD-chunked block swizzle: 1024 blocks, bijective (1024%8==0)
    const int flat = blockIdx.x;
    const int swzb = (flat & 7) * 128 + (flat >> 3);
    const int qtile = swzb & 15;                // q-tile (128 rows)
    const int rest = swzb >> 4;                 // 0..63
    const int bh = rest & 31;                   // batch*head
    const int kvh = rest >> 5;                  // kv half 0/1
    const int b = bh >> 4, h = bh & 15;
    const int q0 = qtile * 128 + wave * 16;
    const int kvbase = kvh * 1024;

    const size_t xbase = (size_t)b * 2048 * 1024 + h * 64;   // qp/kp
    const size_t vbase = (size_t)bh * 64 * 2048;             // vt

    // staging source addressing (pre-swizzled global col, m173 pattern)
    const int sr = lane >> 3;                   // row within 8-row chunk
    const int sc = ((lane & 7) ^ sr) * 8;       // swizzled col (shorts)

    // Q as B-operand frags: col=q(l15), k=d
    short8 bq[2];
    #pragma unroll
    for (int kk = 0; kk < 2; ++kk)
        bq[kk] = *(const short8*)&qp[xbase
            + (size_t)(q0 + l15) * 1024 + kk * 32 + l4 * 8];

    f32x4 acc[4];                   // O^T: [dj]; row=d_local, col=q=l15
    #pragma unroll
    for (int dj = 0; dj < 4; ++dj)
        #pragma unroll
        for (int e = 0; e < 4; ++e) acc[dj][e] = 0.f;

    float m_run = -1e30f, l_part = 0.f;         // l lane-partial

    const int NT = 16;
    for (int t = 0; t < NT; ++t) {
        const int kv0 = kvbase + t * 64;
        __syncthreads();            // all waves done reading prev tile
        {
            const int c = wave;     // chunk 0..7, 8 rows each
            gload_lds16(kp + xbase + (size_t)(kv0 + c * 8 + sr) * 1024 + sc,
                        &Ks[c * 512]);
            gload_lds16(vt + vbase + (size_t)(c * 8 + sr) * 2048 + kv0 + sc,
                        &Vs[c * 512]);
        }
        __syncthreads();            // drains vmcnt -> tile resident

        // ---- S^T = K Q^T ----
        f32x4 st[4];                // kv = j*16 + l4*4 + r ; q = l15
        {
            short8 ak[4];
            #pragma unroll
            for (int j = 0; j < 4; ++j)
                ak[j] = *(const short8*)&Ks[(j * 16 + l15) * 64
                                            + ((l4 << 3) ^ swz)];
            const f32x4 z4 = {0.f, 0.f, 0.f, 0.f};
            #pragma unroll
            for (int j = 0; j < 4; ++j)
                st[j] = __builtin_amdgcn_mfma_f32_16x16x32_bf16(
                    ak[j], bq[0], z4, 0, 0, 0);
            #pragma unroll
            for (int j = 0; j < 4; ++j)
                ak[j] = *(const short8*)&Ks[(j * 16 + l15) * 64
                                            + (((4 + l4) << 3) ^ swz)];
            #pragma unroll
            for (int j = 0; j < 4; ++j)
                st[j] = __builtin_amdgcn_mfma_f32_16x16x32_bf16(
                    ak[j], bq[1], st[j], 0, 0, 0);
        }

        // ---- prefetch V frags from LDS ----
        short8 av[2][4];            // [kvc][dj]
        #pragma unroll
        for (int kvc = 0; kvc < 2; ++kvc)
            #pragma unroll
            for (int dj = 0; dj < 4; ++dj)
                av[kvc][dj] = *(const short8*)&Vs[(dj * 16 + l15) * 64
                                            + (((kvc * 4 + l4) << 3) ^ swz)];

        // ---- in-lane online softmax (exp2 domain), q = l15 lane-local ----
        {
            float tm[4];
            #pragma unroll
            for (int j = 0; j < 4; ++j)
                tm[j] = fmaxf(fmaxf(st[j][0], st[j][1]),
                              fmaxf(st[j][2], st[j][3]));
            float mx = fmaxf(fmaxf(tm[0], tm[1]), fmaxf(tm[2], tm[3]));
            mx = fmaxf(mx, __shfl_xor(mx, 16));
            mx = fmaxf(mx, __shfl_xor(mx, 32));
            const float mnew = fmaxf(m_run, mx);
            const float corr = exp2_fast(m_run - mnew);
            m_run = mnew;
            float ts[4];
            #pragma unroll
            for (int j = 0; j < 4; ++j) {
                float p0 = exp2_fast(st[j][0] - mnew);
                float p1 = exp2_fast(st[j][1] - mnew);
                float p2 = exp2_fast(st[j][2] - mnew);
                float p3 = exp2_fast(st[j][3] - mnew);
                st[j][0] = p0; st[j][1] = p1; st[j][2] = p2; st[j][3] = p3;
                ts[j] = (p0 + p1) + (p2 + p3);
            }
            // lane-partial l: corr uniform across a q-row's 4 lanes
            l_part = l_part * corr + ((ts[0] + ts[1]) + (ts[2] + ts[3]));
            #pragma unroll
            for (int dj = 0; dj < 4; ++dj) acc[dj] *= corr;
        }

        // ---- P^T -> swizzled per-wave LDS (b64 writes) ----
        #pragma unroll
        for (int j = 0; j < 4; ++j) {
            uint2v w;
            w.x = cvt_pk_bf16(st[j][0], st[j][1]);
            w.y = cvt_pk_bf16(st[j][2], st[j][3]);
            *(uint2v*)&P[wave][l15 * 64 + ((j * 16 + l4 * 4) ^ swz)] = w;
        }

        // ---- O^T += V^T P^T ----
        #pragma unroll
        for (int kvc = 0; kvc < 2; ++kvc) {
            short8 pb = *(const short8*)&P[wave][l15 * 64
                                            + (((kvc * 4 + l4) << 3) ^ swz)];
            #pragma unroll
            for (int dj = 0; dj < 4; ++dj)
                acc[dj] = __builtin_amdgcn_mfma_f32_16x16x32_bf16(
                    av[kvc][dj], pb, acc[dj], 0, 0, 0);
        }
    }

    // ---- epilogue: reduce lane-partial l, store UNNORMALIZED partials ----
    {
        float l = l_part;
        l += __shfl_xor(l, 16);
        l += __shfl_xor(l, 32);
        const size_t row = (size_t)bh * 2048 + q0 + l15;
        const size_t base = ((size_t)kvh * 65536 + row) * 64;
        #pragma unroll
        for (int dj = 0; dj < 4; ++dj) {
            uint2v w;
            w.x = cvt_pk_bf16(acc[dj][0], acc[dj][1]);
            w.y = cvt_pk_bf16(acc[dj][2], acc[dj][3]);
            *(uint2v*)&pacc[base + dj * 16 + l4 * 4] = w;
        }
        if (l4 == 0) {
            const size_t mi = ((size_t)kvh * 65536 + row) * 2;
            pml[mi]     = m_run;
            pml[mi + 1] = l;
        }
    }
}

// ---------------------------------------------------------------------------
// Combine the two kv-halves: O = (a0*2^(m0-m*) + a1*2^(m1-m*)) / (l0*2^(m0-m*)
// + l1*2^(m1-m*)).  grid 4096 x 256 thr; 16 rows/block, 16 thr/row (4 d each).
__global__ void attn_combine(const unsigned short* __restrict__ pacc,
                             const float* __restrict__ pml,
                             unsigned short* __restrict__ op)
{
    const int tid = threadIdx.x;
    const int rl = tid >> 4;                    // row within block
    const int dl = (tid & 15) * 4;              // d offset
    const size_t row = (size_t)blockIdx.x * 16 + rl;
    const float m0 = pml[row * 2], l0 = pml[row * 2 + 1];
    const float m1 = pml[(65536 + row) * 2], l1 = pml[(65536 + row) * 2 + 1];
    const float mm = fmaxf(m0, m1);
    const float s0 = exp2_fast(m0 - mm), s1 = exp2_fast(m1 - mm);
    const float inv = 1.0f / (l0 * s0 + l1 * s1);
    const ushort4v a0 = *(const ushort4v*)&pacc[row * 64 + dl];
    const ushort4v a1 = *(const ushort4v*)&pacc[(65536ull + row) * 64 + dl];
    float o[4];
    #pragma unroll
    for (int e = 0; e < 4; ++e)
        o[e] = (bf16_f32(a0[e]) * s0 + bf16_f32(a1[e]) * s1) * inv;
    const int bh = (int)(row >> 11), t = (int)(row & 2047);
    const int b = bh >> 4, h = bh & 15;
    uint2v w;
    w.x = cvt_pk_bf16(o[0], o[1]);
    w.y = cvt_pk_bf16(o[2], o[3]);
    *(uint2v*)&op[((size_t)(b * 2048 + t)) * 1024 + h * 64 + dl] = w;
}

// ---------------------------------------------------------------------------
extern "C" void kernel_launch(void* const* d_in, const int* in_sizes, int n_in,
                              void* d_out, int out_size, void* d_ws, size_t ws_size,
                              hipStream_t stream)
{
    const float* q  = (const float*)d_in[0];
    const float* k  = (const float*)d_in[1];
    const float* v  = (const float*)d_in[2];
    const float* wq = (const float*)d_in[3];
    const float* bq = (const float*)d_in[4];
    const float* wk = (const float*)d_in[5];
    const float* bk = (const float*)d_in[6];
    const float* wv = (const float*)d_in[7];
    const float* bv = (const float*)d_in[8];
    const float* wo = (const float*)d_in[9];
    const float* bo = (const float*)d_in[10];
    float* out = (float*)d_out;

    const int M = 4096, N = 1024, K = 1024;
    unsigned char* ws = (unsigned char*)d_ws;
    const size_t SX = (size_t)M * K * 2;        // 8 MB
    const size_t SW = (size_t)N * K * 2;        // 2 MB
    unsigned short* xq  = (unsigned short*)(ws);
    unsigned short* xk  = (unsigned short*)(ws + SX);
    unsigned short* xv  = (unsigned short*)(ws + 2 * SX);
    unsigned short* wqb = (unsigned short*)(ws + 3 * SX);
    unsigned short* wkb = (unsigned short*)(ws + 3 * SX + SW);
    unsigned short* wvb = (unsigned short*)(ws + 3 * SX + 2 * SW);
    unsigned short* wob = (unsigned short*)(ws + 3 * SX + 3 * SW);
    unsigned short* qp  = (unsigned short*)(ws + 3 * SX + 4 * SW);
    unsigned short* kp  = qp + (size_t)M * N;
    unsigned short* vt  = kp + (size_t)M * N;
    unsigned short* opb = vt + (size_t)M * N;

    // partial buffers overlay xq/xk (16MB) and xv (1MB) — dead after gemm_qkv
    unsigned short* pacc = xq;                  // [2][65536][64] bf16 = 16MB
    float*          pml  = (float*)xv;          // [2][65536][2] fp32 = 1MB

    pack3_bf16<<<dim3(4096, 3), 256, 0, stream>>>(q, k, v, xq, xk, xv,
                                                  M * K / 4);
    pack4_bf16<<<dim3(1024, 4), 256, 0, stream>>>(wq, wk, wv, wo,
                                                  wqb, wkb, wvb, wob, N * K / 4);

    gemm_qkv<<<dim3(8, 32, 3), 256, 0, stream>>>(xq, xk, xv, wqb, wkb, wvb,
                                                 bq, bk, bv, qp, kp, vt);

    attn_fwd<<<dim3(1024), 512, 0, stream>>>(qp, kp, vt, pacc, pml);
    attn_combine<<<dim3(4096), 256, 0, stream>>>(pacc, pml, opb);

    gemm_out<<<dim3(8, 64), 256, 0, stream>>>(opb, wob, bo, out);
}

// Round 17
// 141.884 us; speedup vs baseline: 1.0108x; 1.0108x over previous
//
#include <hip/hip_runtime.h>
#include <math.h>

// ---------------------------------------------------------------------------
// MultiHeadAttention forward, MI355X/gfx950.  Round 17.
//   pack3/pack4: fp32 -> bf16 (frozen)
//   gemm_qkv / gemm_out: R13-exact (T2-swizzled LDS)
//   attn_fwd: R15-EXACT kernel (kv-split, single-buffered, PASSED with
//     absmax 1.4648e-3) with ONE change: launch_bounds (512,8) -> (512,4).
//     R15's (512,8) capped VGPR at 64 -> compiler emitted VGPR=32 + ~18MB
//     scratch spill (WRITE 35.8MB vs 17.4MB of real partials) which ate the
//     occupancy win.  (512,4) is the bound every passing attn used (body
//     compiles 44-60 VGPR, no spill); <=64 VGPR -> 4 blocks/CU = 32 waves.
//     R16's dbuf+(512,6) variant failed validation unexplained -> abandoned.
//   attn_combine: log-sum-exp merge (R15-exact, passed)
// ---------------------------------------------------------------------------

typedef __attribute__((ext_vector_type(8))) short short8;     // 8 x bf16 frag
typedef __attribute__((ext_vector_type(4))) float f32x4;      // MFMA acc
typedef __attribute__((ext_vector_type(4))) float float4v;
typedef __attribute__((ext_vector_type(4))) unsigned short ushort4v;
typedef __attribute__((ext_vector_type(2))) unsigned int uint2v;

typedef __attribute__((address_space(3))) unsigned int lds_uint;
typedef __attribute__((address_space(1))) unsigned int glb_uint;

__device__ __forceinline__ void gload_lds16(const void* g, void* l) {
    __builtin_amdgcn_global_load_lds((glb_uint*)(unsigned long long)g,
                                     (lds_uint*)(unsigned int)(unsigned long long)l,
                                     16, 0, 0);
}

__device__ __forceinline__ unsigned short f32_bf16(float f) {
    union { float f; unsigned int u; } x; x.f = f;
    unsigned int r = x.u + 0x7fffu + ((x.u >> 16) & 1u);   // RNE
    return (unsigned short)(r >> 16);
}

__device__ __forceinline__ float bf16_f32(unsigned short u) {
    union { unsigned int i; float f; } x; x.i = ((unsigned int)u) << 16;
    return x.f;
}

__device__ __forceinline__ unsigned int cvt_pk_bf16(float lo, float hi) {
    unsigned int r;
    asm("v_cvt_pk_bf16_f32 %0, %1, %2" : "=v"(r) : "v"(lo), "v"(hi));
    return r;
}

// single-instruction exp2
__device__ __forceinline__ float exp2_fast(float x) {
    float r;
    asm("v_exp_f32 %0, %1" : "=v"(r) : "v"(x));
    return r;
}

// SCALE * log2(e): folded into Q projection so softmax runs in exp2 domain
#define QSCALE 0.18033688011112042f

// ---------------------------------------------------------------------------
__global__ void pack3_bf16(const float* __restrict__ a, const float* __restrict__ b,
                           const float* __restrict__ c,
                           unsigned short* __restrict__ oa, unsigned short* __restrict__ ob,
                           unsigned short* __restrict__ oc, int n4) {
    const int y = blockIdx.y;
    const float* in = (y == 0) ? a : (y == 1) ? b : c;
    unsigned short* out = (y == 0) ? oa : (y == 1) ? ob : oc;
    int i = blockIdx.x * blockDim.x + threadIdx.x;
    if (i < n4) {
        float4v v = ((const float4v*)in)[i];
        ushort4v o;
        o.x = f32_bf16(v.x); o.y = f32_bf16(v.y);
        o.z = f32_bf16(v.z); o.w = f32_bf16(v.w);
        ((ushort4v*)out)[i] = o;
    }
}

__global__ void pack4_bf16(const float* __restrict__ a, const float* __restrict__ b,
                           const float* __restrict__ c, const float* __restrict__ d,
                           unsigned short* __restrict__ oa, unsigned short* __restrict__ ob,
                           unsigned short* __restrict__ oc, unsigned short* __restrict__ od,
                           int n4) {
    const int y = blockIdx.y;
    const float* in = (y == 0) ? a : (y == 1) ? b : (y == 2) ? c : d;
    unsigned short* out = (y == 0) ? oa : (y == 1) ? ob : (y == 2) ? oc : od;
    int i = blockIdx.x * blockDim.x + threadIdx.x;
    if (i < n4) {
        float4v v = ((const float4v*)in)[i];
        ushort4v o;
        o.x = f32_bf16(v.x); o.y = f32_bf16(v.y);
        o.z = f32_bf16(v.z); o.w = f32_bf16(v.w);
        ((ushort4v*)out)[i] = o;
    }
}

// ---------------------------------------------------------------------------
// Batched QKV projection GEMM (R13-exact: 4 waves + T2 XOR-swizzled LDS).
__global__ __launch_bounds__(256, 2) void gemm_qkv(
    const unsigned short* __restrict__ A0, const unsigned short* __restrict__ A1,
    const unsigned short* __restrict__ A2,
    const unsigned short* __restrict__ W0, const unsigned short* __restrict__ W1,
    const unsigned short* __restrict__ W2,
    const float* __restrict__ bs0, const float* __restrict__ bs1,
    const float* __restrict__ bs2,
    unsigned short* __restrict__ O0, unsigned short* __restrict__ O1,
    unsigned short* __restrict__ O2)
{
    const int z = blockIdx.z;
    const unsigned short* A = (z == 0) ? A0 : (z == 1) ? A1 : A2;
    const unsigned short* W = (z == 0) ? W0 : (z == 1) ? W1 : W2;
    const float* bias        = (z == 0) ? bs0 : (z == 1) ? bs1 : bs2;
    unsigned short* C        = (z == 0) ? O0 : (z == 1) ? O1 : O2;
    const float oscale = (z == 0) ? QSCALE : 1.0f;
    const int N = 1024, K = 1024;

    __shared__ unsigned short As[128 * 64];
    __shared__ unsigned short Bs[128 * 64];
    const int tid  = threadIdx.x;
    const int lane = tid & 63, wave = tid >> 6;
    const int l15 = lane & 15, l4 = lane >> 4;
    const int bm = blockIdx.y * 128, bn = blockIdx.x * 128;
    const int wr = wave >> 1, wc = wave & 1;
    const int swz = l15 & 7;                    // XOR key (8-short units)

    f32x4 acc[4][4];
    #pragma unroll
    for (int i = 0; i < 4; ++i)
        #pragma unroll
        for (int j = 0; j < 4; ++j)
            #pragma unroll
            for (int e = 0; e < 4; ++e) acc[i][j][e] = 0.f;

    const int srow = lane >> 3;                 // row 0..7 within chunk
    const int scol = ((lane & 7) ^ srow) * 8;   // pre-swizzled source col

    for (int k0 = 0; k0 < K; k0 += 64) {
        __syncthreads();
        #pragma unroll
        for (int i = 0; i < 4; ++i) {
            int c = wave * 4 + i;
            int row = c * 8 + srow;
            gload_lds16(A + (size_t)(bm + row) * K + k0 + scol, &As[c * 512]);
            gload_lds16(W + (size_t)(bn + row) * K + k0 + scol, &Bs[c * 512]);
        }
        __syncthreads();
        #pragma unroll
        for (int kk = 0; kk < 2; ++kk) {
            short8 af[4], bf[4];
            const int ko = ((kk * 4 + l4) ^ swz) << 3;   // swizzled col
            #pragma unroll
            for (int i = 0; i < 4; ++i)
                af[i] = *(const short8*)&As[(wr * 64 + i * 16 + l15) * 64 + ko];
            #pragma unroll
            for (int j = 0; j < 4; ++j)
                bf[j] = *(const short8*)&Bs[(wc * 64 + j * 16 + l15) * 64 + ko];
            #pragma unroll
            for (int i = 0; i < 4; ++i)
                #pragma unroll
                for (int j = 0; j < 4; ++j)
                    acc[i][j] = __builtin_amdgcn_mfma_f32_16x16x32_bf16(
                        af[i], bf[j], acc[i][j], 0, 0, 0);
        }
    }

    #pragma unroll
    for (int j = 0; j < 4; ++j) {
        const int col = bn + wc * 64 + j * 16 + l15;
        const float bj = bias[col];
        #pragma unroll
        for (int i = 0; i < 4; ++i) {
            const int row0 = bm + wr * 64 + i * 16 + l4 * 4;
            #pragma unroll
            for (int r = 0; r < 4; ++r) {
                const int row = row0 + r;
                const float v = (acc[i][j][r] + bj) * oscale;
                if (z < 2) {
                    C[(size_t)row * N + col] = f32_bf16(v);
                } else {
                    const int b = row >> 11, t = row & 2047;
                    C[(((size_t)((b << 4) + (col >> 6)) * 64
                        + (col & 63)) << 11) + t] = f32_bf16(v);
                }
            }
        }
    }
}

// ---------------------------------------------------------------------------
// Output-projection GEMM (fp32 out).  R13-exact: 64x128 dbuf + T2 swizzle.
__global__ __launch_bounds__(256, 3) void gemm_out(
    const unsigned short* __restrict__ A,
    const unsigned short* __restrict__ W,
    const float* __restrict__ bias,
    float* __restrict__ C)
{
    const int N = 1024, K = 1024;
    __shared__ unsigned short As[2][64 * 64];
    __shared__ unsigned short Bs[2][128 * 64];
    const int tid  = threadIdx.x;
    const int lane = tid & 63, wave = tid >> 6;
    const int l15 = lane & 15, l4 = lane >> 4;
    const int bm = blockIdx.y * 64, bn = blockIdx.x * 128;
    const int wr = wave >> 1, wc = wave & 1;
    const int swz = l15 & 7;

    f32x4 acc[2][4];
    #pragma unroll
    for (int i = 0; i < 2; ++i)
        #pragma unroll
        for (int j = 0; j < 4; ++j)
            #pragma unroll
            for (int e = 0; e < 4; ++e) acc[i][j][e] = 0.f;

    const int srow = lane >> 3;
    const int scol = ((lane & 7) ^ srow) * 8;

    auto stage = [&](int bf, int k0) {
        #pragma unroll
        for (int i = 0; i < 2; ++i) {
            const int c = wave * 2 + i;
            gload_lds16(A + (size_t)(bm + c * 8 + srow) * K + k0 + scol,
                        &As[bf][c * 512]);
        }
        #pragma unroll
        for (int i = 0; i < 4; ++i) {
            const int c = wave * 4 + i;
            gload_lds16(W + (size_t)(bn + c * 8 + srow) * K + k0 + scol,
                        &Bs[bf][c * 512]);
        }
    };

    stage(0, 0);
    __syncthreads();

    int bufi = 0;
    for (int k0 = 0; k0 < K; k0 += 64) {
        if (k0 + 64 < K) stage(bufi ^ 1, k0 + 64);
        #pragma unroll
        for (int kk = 0; kk < 2; ++kk) {
            short8 af[2], bf[4];
            const int ko = ((kk * 4 + l4) ^ swz) << 3;
            #pragma unroll
            for (int i = 0; i < 2; ++i)
                af[i] = *(const short8*)&As[bufi][(wr * 32 + i * 16 + l15) * 64 + ko];
            #pragma unroll
            for (int j = 0; j < 4; ++j)
                bf[j] = *(const short8*)&Bs[bufi][(wc * 64 + j * 16 + l15) * 64 + ko];
            #pragma unroll
            for (int i = 0; i < 2; ++i)
                #pragma unroll
                for (int j = 0; j < 4; ++j)
                    acc[i][j] = __builtin_amdgcn_mfma_f32_16x16x32_bf16(
                        af[i], bf[j], acc[i][j], 0, 0, 0);
        }
        __syncthreads();
        bufi ^= 1;
    }

    #pragma unroll
    for (int j = 0; j < 4; ++j) {
        const int col = bn + wc * 64 + j * 16 + l15;
        const float bj = bias[col];
        #pragma unroll
        for (int i = 0; i < 2; ++i) {
            const int row0 = bm + wr * 32 + i * 16 + l4 * 4;
            #pragma unroll
            for (int r = 0; r < 4; ++r)
                C[(size_t)(row0 + r) * N + col] = acc[i][j][r] + bj;
        }
    }
}

// ---------------------------------------------------------------------------
// Flash attention, R17 = R15-EXACT kv-split kernel (passed, absmax 1.4648e-3)
// with launch_bounds (512,4) instead of (512,8): no artificial VGPR cap ->
// no spill.  grid 1024 = (bh 32)x(qtile 16)x(kvhalf 2), 8 waves x 16 q-rows,
// 1024 kv/block in 16 single-buffered 64-kv tiles, LDS 32KB.
__global__ __launch_bounds__(512, 4) void attn_fwd(
    const unsigned short* __restrict__ qp,
    const unsigned short* __restrict__ kp,
    const unsigned short* __restrict__ vt,
    unsigned short* __restrict__ pacc,   // [2][65536][64] bf16
    float* __restrict__ pml)             // [2][65536][2]  {m, l}
{
    __shared__ unsigned short Ks[64 * 64];      // [kv][d]  swizzled
    __shared__ unsigned short Vs[64 * 64];      // [d][kv]  swizzled
    __shared__ unsigned short P[8][16 * 64];    // [wave][q][kv] swizzled

    const int tid = threadIdx.x;
    const int lane = tid & 63, wave = tid >> 6;  // wave 0..7
    const int l15 = lane & 15, l4 = lane >> 4;
    const int swz = (l15 & 7) << 3;             // XOR mask in short units

    // XCD-chunked block swizzle: 1024 blocks, bijective (1024%8==0)
    const int flat = blockIdx.x;
    const int swzb = (flat & 7) * 128 + (flat >> 3);
    const int qtile = swzb & 15;                // q-tile (128 rows)
    const int rest = swzb >> 4;                 // 0..63
    const int bh = rest & 31;                   // batch*head
    const int kvh = rest >> 5;                  // kv half 0/1
    const int b = bh >> 4, h = bh & 15;
    const int q0 = qtile * 128 + wave * 16;
    const int kvbase = kvh * 1024;

    const size_t xbase = (size_t)b * 2048 * 1024 + h * 64;   // qp/kp
    const size_t vbase = (size_t)bh * 64 * 2048;             // vt

    // staging source addressing (pre-swizzled global col, m173 pattern)
    const int sr = lane >> 3;                   // row within 8-row chunk
    const int sc = ((lane & 7) ^ sr) * 8;       // swizzled col (shorts)

    // Q as B-operand frags: col=q(l15), k=d
    short8 bq[2];
    #pragma unroll
    for (int kk = 0; kk < 2; ++kk)
        bq[kk] = *(const short8*)&qp[xbase
            + (size_t)(q0 + l15) * 1024 + kk * 32 + l4 * 8];

    f32x4 acc[4];                   // O^T: [dj]; row=d_local, col=q=l15
    #pragma unroll
    for (int dj = 0; dj < 4; ++dj)
        #pragma unroll
        for (int e = 0; e < 4; ++e) acc[dj][e] = 0.f;

    float m_run = -1e30f, l_part = 0.f;         // l lane-partial

    const int NT = 16;
    for (int t = 0; t < NT; ++t) {
        const int kv0 = kvbase + t * 64;
        __syncthreads();            // all waves done reading prev tile
        {
            const int c = wave;     // chunk 0..7, 8 rows each
            gload_lds16(kp + xbase + (size_t)(kv0 + c * 8 + sr) * 1024 + sc,
                        &Ks[c * 512]);
            gload_lds16(vt + vbase + (size_t)(c * 8 + sr) * 2048 + kv0 + sc,
                        &Vs[c * 512]);
        }
        __syncthreads();            // drains vmcnt -> tile resident

        // ---- S^T = K Q^T ----
        f32x4 st[4];                // kv = j*16 + l4*4 + r ; q = l15
        {
            short8 ak[4];
            #pragma unroll
            for (int j = 0; j < 4; ++j)
                ak[j] = *(const short8*)&Ks[(j * 16 + l15) * 64
                                            + ((l4 << 3) ^ swz)];
            const f32x4 z4 = {0.f, 0.f, 0.f, 0.f};
            #pragma unroll
            for (int j = 0; j < 4; ++j)
                st[j] = __builtin_amdgcn_mfma_f32_16x16x32_bf16(
                    ak[j], bq[0], z4, 0, 0, 0);
            #pragma unroll
            for (int j = 0; j < 4; ++j)
                ak[j] = *(const short8*)&Ks[(j * 16 + l15) * 64
                                            + (((4 + l4) << 3) ^ swz)];
            #pragma unroll
            for (int j = 0; j < 4; ++j)
                st[j] = __builtin_amdgcn_mfma_f32_16x16x32_bf16(
                    ak[j], bq[1], st[j], 0, 0, 0);
        }

        // ---- prefetch V frags from LDS ----
        short8 av[2][4];            // [kvc][dj]
        #pragma unroll
        for (int kvc = 0; kvc < 2; ++kvc)
            #pragma unroll
            for (int dj = 0; dj < 4; ++dj)
                av[kvc][dj] = *(const short8*)&Vs[(dj * 16 + l15) * 64
                                            + (((kvc * 4 + l4) << 3) ^ swz)];

        // ---- in-lane online softmax (exp2 domain), q = l15 lane-local ----
        {
            float tm[4];
            #pragma unroll
            for (int j = 0; j < 4; ++j)
                tm[j] = fmaxf(fmaxf(st[j][0], st[j][1]),
                              fmaxf(st[j][2], st[j][3]));
            float mx = fmaxf(fmaxf(tm[0], tm[1]), fmaxf(tm[2], tm[3]));
            mx = fmaxf(mx, __shfl_xor(mx, 16));
            mx = fmaxf(mx, __shfl_xor(mx, 32));
            const float mnew = fmaxf(m_run, mx);
            const float corr = exp2_fast(m_run - mnew);
            m_run = mnew;
            float ts[4];
            #pragma unroll
            for (int j = 0; j < 4; ++j) {
                float p0 = exp2_fast(st[j][0] - mnew);
                float p1 = exp2_fast(st[j][1] - mnew);
                float p2 = exp2_fast(st[j][2] - mnew);
                float p3 = exp2_fast(st[j][3] - mnew);
                st[j][0] = p0; st[j][1] = p1; st[j][2] = p2; st[j][3] = p3;
                ts[j] = (p0 + p1) + (p2 + p3);
            }
            // lane-partial l: corr uniform across a q-row's 4 lanes
            l_part = l_part * corr + ((ts[0] + ts[1]) + (ts[2] + ts[3]));
            #pragma unroll
            for (int dj = 0; dj < 4; ++dj) acc[dj] *= corr;
        }

        // ---- P^T -> swizzled per-wave LDS (b64 writes) ----
        #pragma unroll
        for (int j = 0; j < 4; ++j) {
            uint2v w;
            w.x = cvt_pk_bf16(st[j][0], st[j][1]);
            w.y = cvt_pk_bf16(st[j][2], st[j][3]);
            *(uint2v*)&P[wave][l15 * 64 + ((j * 16 + l4 * 4) ^ swz)] = w;
        }

        // ---- O^T += V^T P^T ----
        #pragma unroll
        for (int kvc = 0; kvc < 2; ++kvc) {
            short8 pb = *(const short8*)&P[wave][l15 * 64
                                            + (((kvc * 4 + l4) << 3) ^ swz)];
            #pragma unroll
            for (int dj = 0; dj < 4; ++dj)
                acc[dj] = __builtin_amdgcn_mfma_f32_16x16x32_bf16(
                    av[kvc][dj], pb, acc[dj], 0, 0, 0);
        }
    }

    // ---- epilogue: reduce lane-partial l, store UNNORMALIZED partials ----
    {
        float l = l_part;
        l += __shfl_xor(l, 16);
        l += __shfl_xor(l, 32);
        const size_t row = (size_t)bh * 2048 + q0 + l15;
        const size_t base = ((size_t)kvh * 65536 + row) * 64;
        #pragma unroll
        for (int dj = 0; dj < 4; ++dj) {
            uint2v w;
            w.x = cvt_pk_bf16(acc[dj][0], acc[dj][1]);
            w.y = cvt_pk_bf16(acc[dj][2], acc[dj][3]);
            *(uint2v*)&pacc[base + dj * 16 + l4 * 4] = w;
        }
        if (l4 == 0) {
            const size_t mi = ((size_t)kvh * 65536 + row) * 2;
            pml[mi]     = m_run;
            pml[mi + 1] = l;
        }
    }
}

// ---------------------------------------------------------------------------
// Combine the two kv-halves (R15-exact, proven).  grid 4096 x 256 thr.
__global__ void attn_combine(const unsigned short* __restrict__ pacc,
                             const float* __restrict__ pml,
                             unsigned short* __restrict__ op)
{
    const int tid = threadIdx.x;
    const int rl = tid >> 4;                    // row within block
    const int dl = (tid & 15) * 4;              // d offset
    const size_t row = (size_t)blockIdx.x * 16 + rl;
    const float m0 = pml[row * 2], l0 = pml[row * 2 + 1];
    const float m1 = pml[(65536 + row) * 2], l1 = pml[(65536 + row) * 2 + 1];
    const float mm = fmaxf(m0, m1);
    const float s0 = exp2_fast(m0 - mm), s1 = exp2_fast(m1 - mm);
    const float inv = 1.0f / (l0 * s0 + l1 * s1);
    const ushort4v a0 = *(const ushort4v*)&pacc[row * 64 + dl];
    const ushort4v a1 = *(const ushort4v*)&pacc[(65536ull + row) * 64 + dl];
    float o[4];
    #pragma unroll
    for (int e = 0; e < 4; ++e)
        o[e] = (bf16_f32(a0[e]) * s0 + bf16_f32(a1[e]) * s1) * inv;
    const int bh = (int)(row >> 11), t = (int)(row & 2047);
    const int b = bh >> 4, h = bh & 15;
    uint2v w;
    w.x = cvt_pk_bf16(o[0], o[1]);
    w.y = cvt_pk_bf16(o[2], o[3]);
    *(uint2v*)&op[((size_t)(b * 2048 + t)) * 1024 + h * 64 + dl] = w;
}

// ---------------------------------------------------------------------------
extern "C" void kernel_launch(void* const* d_in, const int* in_sizes, int n_in,
                              void* d_out, int out_size, void* d_ws, size_t ws_size,
                              hipStream_t stream)
{
    const float* q  = (const float*)d_in[0];
    const float* k  = (const float*)d_in[1];
    const float* v  = (const float*)d_in[2];
    const float* wq = (const float*)d_in[3];
    const float* bq = (const float*)d_in[4];
    const float* wk = (const float*)d_in[5];
    const float* bk = (const float*)d_in[6];
    const float* wv = (const float*)d_in[7];
    const float* bv = (const float*)d_in[8];
    const float* wo = (const float*)d_in[9];
    const float* bo = (const float*)d_in[10];
    float* out = (float*)d_out;

    const int M = 4096, N = 1024, K = 1024;
    unsigned char* ws = (unsigned char*)d_ws;
    const size_t SX = (size_t)M * K * 2;        // 8 MB
    const size_t SW = (size_t)N * K * 2;        // 2 MB
    unsigned short* xq  = (unsigned short*)(ws);
    unsigned short* xk  = (unsigned short*)(ws + SX);
    unsigned short* xv  = (unsigned short*)(ws + 2 * SX);
    unsigned short* wqb = (unsigned short*)(ws + 3 * SX);
    unsigned short* wkb = (unsigned short*)(ws + 3 * SX + SW);
    unsigned short* wvb = (unsigned short*)(ws + 3 * SX + 2 * SW);
    unsigned short* wob = (unsigned short*)(ws + 3 * SX + 3 * SW);
    unsigned short* qp  = (unsigned short*)(ws + 3 * SX + 4 * SW);
    unsigned short* kp  = qp + (size_t)M * N;
    unsigned short* vt  = kp + (size_t)M * N;
    unsigned short* opb = vt + (size_t)M * N;

    // partial buffers overlay xq/xk (16MB) and xv (1MB) — dead after gemm_qkv
    unsigned short* pacc = xq;                  // [2][65536][64] bf16 = 16MB
    float*          pml  = (float*)xv;          // [2][65536][2] fp32 = 1MB

    pack3_bf16<<<dim3(4096, 3), 256, 0, stream>>>(q, k, v, xq, xk, xv,
                                                  M * K / 4);
    pack4_bf16<<<dim3(1024, 4), 256, 0, stream>>>(wq, wk, wv, wo,
                                                  wqb, wkb, wvb, wob, N * K / 4);

    gemm_qkv<<<dim3(8, 32, 3), 256, 0, stream>>>(xq, xk, xv, wqb, wkb, wvb,
                                                 bq, bk, bv, qp, kp, vt);

    attn_fwd<<<dim3(1024), 512, 0, stream>>>(qp, kp, vt, pacc, pml);
    attn_combine<<<dim3(4096), 256, 0, stream>>>(pacc, pml, opb);

    gemm_out<<<dim3(8, 64), 256, 0, stream>>>(opb, wob, bo, out);
}

// Round 18
// 128.662 us; speedup vs baseline: 1.1147x; 1.1028x over previous
//
#include <hip/hip_runtime.h>
#include <math.h>

// ---------------------------------------------------------------------------
// MultiHeadAttention forward, MI355X/gfx950.  Round 18.
//   = R14 (best verified, 130.0us) + T13 defer-max in attn softmax.
//   pack3/pack4: fp32 -> bf16 (frozen, HBM-roofline)
//   gemm_qkv / gemm_out: R13-exact (T2-swizzled LDS)
//   attn_fwd: R14 structure (8 waves, KVBLK=128 staged/iter as two 64-halves,
//     dbuf, 80KB LDS) + defer-max: skip corr/rescale when the tile max stays
//     within THR=8 of the running max (wave-uniform branch; P bounded by
//     2^8, l/acc scale identically -> normalized output unchanged).
//   kv-split abandoned: R17 proved spill-free split (69+4us) < R14 (63us).
// ---------------------------------------------------------------------------

typedef __attribute__((ext_vector_type(8))) short short8;     // 8 x bf16 frag
typedef __attribute__((ext_vector_type(4))) float f32x4;      // MFMA acc
typedef __attribute__((ext_vector_type(4))) float float4v;
typedef __attribute__((ext_vector_type(4))) unsigned short ushort4v;
typedef __attribute__((ext_vector_type(2))) unsigned int uint2v;

typedef __attribute__((address_space(3))) unsigned int lds_uint;
typedef __attribute__((address_space(1))) unsigned int glb_uint;

__device__ __forceinline__ void gload_lds16(const void* g, void* l) {
    __builtin_amdgcn_global_load_lds((glb_uint*)(unsigned long long)g,
                                     (lds_uint*)(unsigned int)(unsigned long long)l,
                                     16, 0, 0);
}

__device__ __forceinline__ unsigned short f32_bf16(float f) {
    union { float f; unsigned int u; } x; x.f = f;
    unsigned int r = x.u + 0x7fffu + ((x.u >> 16) & 1u);   // RNE
    return (unsigned short)(r >> 16);
}

__device__ __forceinline__ unsigned int cvt_pk_bf16(float lo, float hi) {
    unsigned int r;
    asm("v_cvt_pk_bf16_f32 %0, %1, %2" : "=v"(r) : "v"(lo), "v"(hi));
    return r;
}

// single-instruction exp2
__device__ __forceinline__ float exp2_fast(float x) {
    float r;
    asm("v_exp_f32 %0, %1" : "=v"(r) : "v"(x));
    return r;
}

// SCALE * log2(e): folded into Q projection so softmax runs in exp2 domain
#define QSCALE 0.18033688011112042f

// ---------------------------------------------------------------------------
__global__ void pack3_bf16(const float* __restrict__ a, const float* __restrict__ b,
                           const float* __restrict__ c,
                           unsigned short* __restrict__ oa, unsigned short* __restrict__ ob,
                           unsigned short* __restrict__ oc, int n4) {
    const int y = blockIdx.y;
    const float* in = (y == 0) ? a : (y == 1) ? b : c;
    unsigned short* out = (y == 0) ? oa : (y == 1) ? ob : oc;
    int i = blockIdx.x * blockDim.x + threadIdx.x;
    if (i < n4) {
        float4v v = ((const float4v*)in)[i];
        ushort4v o;
        o.x = f32_bf16(v.x); o.y = f32_bf16(v.y);
        o.z = f32_bf16(v.z); o.w = f32_bf16(v.w);
        ((ushort4v*)out)[i] = o;
    }
}

__global__ void pack4_bf16(const float* __restrict__ a, const float* __restrict__ b,
                           const float* __restrict__ c, const float* __restrict__ d,
                           unsigned short* __restrict__ oa, unsigned short* __restrict__ ob,
                           unsigned short* __restrict__ oc, unsigned short* __restrict__ od,
                           int n4) {
    const int y = blockIdx.y;
    const float* in = (y == 0) ? a : (y == 1) ? b : (y == 2) ? c : d;
    unsigned short* out = (y == 0) ? oa : (y == 1) ? ob : (y == 2) ? oc : od;
    int i = blockIdx.x * blockDim.x + threadIdx.x;
    if (i < n4) {
        float4v v = ((const float4v*)in)[i];
        ushort4v o;
        o.x = f32_bf16(v.x); o.y = f32_bf16(v.y);
        o.z = f32_bf16(v.z); o.w = f32_bf16(v.w);
        ((ushort4v*)out)[i] = o;
    }
}

// ---------------------------------------------------------------------------
// Batched QKV projection GEMM (R13-exact: 4 waves + T2 XOR-swizzled LDS).
__global__ __launch_bounds__(256, 2) void gemm_qkv(
    const unsigned short* __restrict__ A0, const unsigned short* __restrict__ A1,
    const unsigned short* __restrict__ A2,
    const unsigned short* __restrict__ W0, const unsigned short* __restrict__ W1,
    const unsigned short* __restrict__ W2,
    const float* __restrict__ bs0, const float* __restrict__ bs1,
    const float* __restrict__ bs2,
    unsigned short* __restrict__ O0, unsigned short* __restrict__ O1,
    unsigned short* __restrict__ O2)
{
    const int z = blockIdx.z;
    const unsigned short* A = (z == 0) ? A0 : (z == 1) ? A1 : A2;
    const unsigned short* W = (z == 0) ? W0 : (z == 1) ? W1 : W2;
    const float* bias        = (z == 0) ? bs0 : (z == 1) ? bs1 : bs2;
    unsigned short* C        = (z == 0) ? O0 : (z == 1) ? O1 : O2;
    const float oscale = (z == 0) ? QSCALE : 1.0f;
    const int N = 1024, K = 1024;

    __shared__ unsigned short As[128 * 64];
    __shared__ unsigned short Bs[128 * 64];
    const int tid  = threadIdx.x;
    const int lane = tid & 63, wave = tid >> 6;
    const int l15 = lane & 15, l4 = lane >> 4;
    const int bm = blockIdx.y * 128, bn = blockIdx.x * 128;
    const int wr = wave >> 1, wc = wave & 1;
    const int swz = l15 & 7;                    // XOR key (8-short units)

    f32x4 acc[4][4];
    #pragma unroll
    for (int i = 0; i < 4; ++i)
        #pragma unroll
        for (int j = 0; j < 4; ++j)
            #pragma unroll
            for (int e = 0; e < 4; ++e) acc[i][j][e] = 0.f;

    const int srow = lane >> 3;                 // row 0..7 within chunk
    const int scol = ((lane & 7) ^ srow) * 8;   // pre-swizzled source col

    for (int k0 = 0; k0 < K; k0 += 64) {
        __syncthreads();
        #pragma unroll
        for (int i = 0; i < 4; ++i) {
            int c = wave * 4 + i;
            int row = c * 8 + srow;
            gload_lds16(A + (size_t)(bm + row) * K + k0 + scol, &As[c * 512]);
            gload_lds16(W + (size_t)(bn + row) * K + k0 + scol, &Bs[c * 512]);
        }
        __syncthreads();
        #pragma unroll
        for (int kk = 0; kk < 2; ++kk) {
            short8 af[4], bf[4];
            const int ko = ((kk * 4 + l4) ^ swz) << 3;   // swizzled col
            #pragma unroll
            for (int i = 0; i < 4; ++i)
                af[i] = *(const short8*)&As[(wr * 64 + i * 16 + l15) * 64 + ko];
            #pragma unroll
            for (int j = 0; j < 4; ++j)
                bf[j] = *(const short8*)&Bs[(wc * 64 + j * 16 + l15) * 64 + ko];
            #pragma unroll
            for (int i = 0; i < 4; ++i)
                #pragma unroll
                for (int j = 0; j < 4; ++j)
                    acc[i][j] = __builtin_amdgcn_mfma_f32_16x16x32_bf16(
                        af[i], bf[j], acc[i][j], 0, 0, 0);
        }
    }

    #pragma unroll
    for (int j = 0; j < 4; ++j) {
        const int col = bn + wc * 64 + j * 16 + l15;
        const float bj = bias[col];
        #pragma unroll
        for (int i = 0; i < 4; ++i) {
            const int row0 = bm + wr * 64 + i * 16 + l4 * 4;
            #pragma unroll
            for (int r = 0; r < 4; ++r) {
                const int row = row0 + r;
                const float v = (acc[i][j][r] + bj) * oscale;
                if (z < 2) {
                    C[(size_t)row * N + col] = f32_bf16(v);
                } else {
                    const int b = row >> 11, t = row & 2047;
                    C[(((size_t)((b << 4) + (col >> 6)) * 64
                        + (col & 63)) << 11) + t] = f32_bf16(v);
                }
            }
        }
    }
}

// ---------------------------------------------------------------------------
// Output-projection GEMM (fp32 out).  R13-exact: 64x128 dbuf + T2 swizzle.
__global__ __launch_bounds__(256, 3) void gemm_out(
    const unsigned short* __restrict__ A,
    const unsigned short* __restrict__ W,
    const float* __restrict__ bias,
    float* __restrict__ C)
{
    const int N = 1024, K = 1024;
    __shared__ unsigned short As[2][64 * 64];
    __shared__ unsigned short Bs[2][128 * 64];
    const int tid  = threadIdx.x;
    const int lane = tid & 63, wave = tid >> 6;
    const int l15 = lane & 15, l4 = lane >> 4;
    const int bm = blockIdx.y * 64, bn = blockIdx.x * 128;
    const int wr = wave >> 1, wc = wave & 1;
    const int swz = l15 & 7;

    f32x4 acc[2][4];
    #pragma unroll
    for (int i = 0; i < 2; ++i)
        #pragma unroll
        for (int j = 0; j < 4; ++j)
            #pragma unroll
            for (int e = 0; e < 4; ++e) acc[i][j][e] = 0.f;

    const int srow = lane >> 3;
    const int scol = ((lane & 7) ^ srow) * 8;

    auto stage = [&](int bf, int k0) {
        #pragma unroll
        for (int i = 0; i < 2; ++i) {
            const int c = wave * 2 + i;
            gload_lds16(A + (size_t)(bm + c * 8 + srow) * K + k0 + scol,
                        &As[bf][c * 512]);
        }
        #pragma unroll
        for (int i = 0; i < 4; ++i) {
            const int c = wave * 4 + i;
            gload_lds16(W + (size_t)(bn + c * 8 + srow) * K + k0 + scol,
                        &Bs[bf][c * 512]);
        }
    };

    stage(0, 0);
    __syncthreads();

    int bufi = 0;
    for (int k0 = 0; k0 < K; k0 += 64) {
        if (k0 + 64 < K) stage(bufi ^ 1, k0 + 64);
        #pragma unroll
        for (int kk = 0; kk < 2; ++kk) {
            short8 af[2], bf[4];
            const int ko = ((kk * 4 + l4) ^ swz) << 3;
            #pragma unroll
            for (int i = 0; i < 2; ++i)
                af[i] = *(const short8*)&As[bufi][(wr * 32 + i * 16 + l15) * 64 + ko];
            #pragma unroll
            for (int j = 0; j < 4; ++j)
                bf[j] = *(const short8*)&Bs[bufi][(wc * 64 + j * 16 + l15) * 64 + ko];
            #pragma unroll
            for (int i = 0; i < 2; ++i)
                #pragma unroll
                for (int j = 0; j < 4; ++j)
                    acc[i][j] = __builtin_amdgcn_mfma_f32_16x16x32_bf16(
                        af[i], bf[j], acc[i][j], 0, 0, 0);
        }
        __syncthreads();
        bufi ^= 1;
    }

    #pragma unroll
    for (int j = 0; j < 4; ++j) {
        const int col = bn + wc * 64 + j * 16 + l15;
        const float bj = bias[col];
        #pragma unroll
        for (int i = 0; i < 2; ++i) {
            const int row0 = bm + wr * 32 + i * 16 + l4 * 4;
            #pragma unroll
            for (int r = 0; r < 4; ++r)
                C[(size_t)(row0 + r) * N + col] = acc[i][j][r] + bj;
        }
    }
}

// ---------------------------------------------------------------------------
// Flash attention, R18 = R14 + T13 defer-max.  8 waves/block, 512 blocks.
// KVBLK=128 staged per iteration (16 iterations), computed as two sequential
// 64-kv halves with R9's register set.  Rescale skipped when the half-tile
// max stays within THR=8 of the running max (wave-uniform branch; P <= 2^8).
__global__ __launch_bounds__(512, 4) void attn_fwd(
    const unsigned short* __restrict__ qp,
    const unsigned short* __restrict__ kp,
    const unsigned short* __restrict__ vt,
    unsigned short* __restrict__ op)
{
    __shared__ unsigned short Ks[2][128 * 64];  // [buf][kv 0..127][d] swizzled
    __shared__ unsigned short Vs[2][2][64 * 64];// [buf][half][d][kv]  swizzled
    __shared__ unsigned short P[8][16 * 64];    // [wave][q][kv]       swizzled

    const int tid = threadIdx.x;
    const int lane = tid & 63, wave = tid >> 6;  // wave 0..7
    const int l15 = lane & 15, l4 = lane >> 4;
    const int swz = (l15 & 7) << 3;             // XOR mask in short units

    // XCD-chunked block swizzle: 512 blocks, bijective (512%8==0)
    const int flat = blockIdx.x;
    const int swzb = (flat & 7) * 64 + (flat >> 3);
    const int bx = swzb & 15;                   // q-tile index (128 rows)
    const int bh = swzb >> 4;                   // batch*head
    const int b = bh >> 4, h = bh & 15;
    const int q0 = bx * 128 + wave * 16;

    const size_t xbase = (size_t)b * 2048 * 1024 + h * 64;   // qp/kp
    const size_t vbase = (size_t)bh * 64 * 2048;             // vt

    // staging source addressing (pre-swizzled global col, m173 pattern)
    const int sr = lane >> 3;                   // row within 8-row chunk
    const int sc = ((lane & 7) ^ sr) * 8;       // swizzled col (shorts)

    // Q as B-operand frags: col=q(l15), k=d
    short8 bq[2];
    #pragma unroll
    for (int kk = 0; kk < 2; ++kk)
        bq[kk] = *(const short8*)&qp[xbase
            + (size_t)(q0 + l15) * 1024 + kk * 32 + l4 * 8];

    f32x4 acc[4];                   // O^T: [dj]; row=d_local, col=q=l15
    #pragma unroll
    for (int dj = 0; dj < 4; ++dj)
        #pragma unroll
        for (int e = 0; e < 4; ++e) acc[dj][e] = 0.f;

    float m_run = -1e30f, l_part = 0.f;         // l lane-partial (16 kv/lane)

    // staging: K = 16 chunks (2/wave), V = 2 halves x 8 chunks (2/wave total)
    auto stage = [&](int bf, int kv0) {
        #pragma unroll
        for (int i = 0; i < 2; ++i) {
            const int c = wave * 2 + i;
            gload_lds16(kp + xbase + (size_t)(kv0 + c * 8 + sr) * 1024 + sc,
                        &Ks[bf][c * 512]);
        }
        #pragma unroll
        for (int h2 = 0; h2 < 2; ++h2)
            gload_lds16(vt + vbase + (size_t)(wave * 8 + sr) * 2048
                            + kv0 + h2 * 64 + sc,
                        &Vs[bf][h2][wave * 512]);
    };

    // ---- prologue: stage tile 0 into buf 0 ----
    stage(0, 0);
    __syncthreads();

    const int NT = 2048 / 128;
    int buf = 0;
    for (int t = 0; t < NT; ++t) {
        // ---- stage next 128-kv tile into buf^1 ----
        if (t + 1 < NT) stage(buf ^ 1, (t + 1) * 128);

        #pragma unroll
        for (int hh = 0; hh < 2; ++hh) {
            // ---- S^T = K Q^T for this 64-kv half ----
            f32x4 st[4];            // kv = hh*64 + j*16 + l4*4 + r ; q = l15
            {
                short8 ak[4];
                #pragma unroll
                for (int j = 0; j < 4; ++j)
                    ak[j] = *(const short8*)&Ks[buf][(hh * 64 + j * 16 + l15) * 64
                                                     + ((l4 << 3) ^ swz)];
                const f32x4 z4 = {0.f, 0.f, 0.f, 0.f};
                #pragma unroll
                for (int j = 0; j < 4; ++j)
                    st[j] = __builtin_amdgcn_mfma_f32_16x16x32_bf16(
                        ak[j], bq[0], z4, 0, 0, 0);
                #pragma unroll
                for (int j = 0; j < 4; ++j)
                    ak[j] = *(const short8*)&Ks[buf][(hh * 64 + j * 16 + l15) * 64
                                                     + (((4 + l4) << 3) ^ swz)];
                #pragma unroll
                for (int j = 0; j < 4; ++j)
                    st[j] = __builtin_amdgcn_mfma_f32_16x16x32_bf16(
                        ak[j], bq[1], st[j], 0, 0, 0);
            }

            // ---- prefetch V frags for this half ----
            short8 av[2][4];        // [kvc][dj]
            #pragma unroll
            for (int kvc = 0; kvc < 2; ++kvc)
                #pragma unroll
                for (int dj = 0; dj < 4; ++dj)
                    av[kvc][dj] = *(const short8*)&Vs[buf][hh]
                        [(dj * 16 + l15) * 64 + (((kvc * 4 + l4) << 3) ^ swz)];

            // ---- in-lane online softmax (exp2 domain) + T13 defer-max ----
            {
                float tm[4];
                #pragma unroll
                for (int j = 0; j < 4; ++j)
                    tm[j] = fmaxf(fmaxf(st[j][0], st[j][1]),
                                  fmaxf(st[j][2], st[j][3]));
                float mx = fmaxf(fmaxf(tm[0], tm[1]), fmaxf(tm[2], tm[3]));
                mx = fmaxf(mx, __shfl_xor(mx, 16));
                mx = fmaxf(mx, __shfl_xor(mx, 32));
                // T13: only rescale when some lane's max grew past THR=8
                if (!__all(mx - m_run <= 8.0f)) {
                    const float mnew = fmaxf(m_run, mx);
                    const float corr = exp2_fast(m_run - mnew);
                    m_run = mnew;
                    l_part *= corr;
                    #pragma unroll
                    for (int dj = 0; dj < 4; ++dj) acc[dj] *= corr;
                }
                float ts[4];
                #pragma unroll
                for (int j = 0; j < 4; ++j) {
                    float p0 = exp2_fast(st[j][0] - m_run);
                    float p1 = exp2_fast(st[j][1] - m_run);
                    float p2 = exp2_fast(st[j][2] - m_run);
                    float p3 = exp2_fast(st[j][3] - m_run);
                    st[j][0] = p0; st[j][1] = p1;
                    st[j][2] = p2; st[j][3] = p3;
                    ts[j] = (p0 + p1) + (p2 + p3);
                }
                l_part += (ts[0] + ts[1]) + (ts[2] + ts[3]);
            }

            // ---- P^T -> swizzled per-wave LDS (b64 writes) ----
            #pragma unroll
            for (int j = 0; j < 4; ++j) {
                uint2v w;
                w.x = cvt_pk_bf16(st[j][0], st[j][1]);
                w.y = cvt_pk_bf16(st[j][2], st[j][3]);
                *(uint2v*)&P[wave][l15 * 64 + ((j * 16 + l4 * 4) ^ swz)] = w;
            }

            // ---- O^T += V^T P^T ----
            #pragma unroll
            for (int kvc = 0; kvc < 2; ++kvc) {
                short8 pb = *(const short8*)&P[wave][l15 * 64
                                                + (((kvc * 4 + l4) << 3) ^ swz)];
                #pragma unroll
                for (int dj = 0; dj < 4; ++dj)
                    acc[dj] = __builtin_amdgcn_mfma_f32_16x16x32_bf16(
                        av[kvc][dj], pb, acc[dj], 0, 0, 0);
            }
        }

        __syncthreads();            // drains vmcnt (staging done) + LDS reads
        buf ^= 1;
    }

    // ---- epilogue: reduce lane-partial l, divide, 8B vector stores ----
    {
        float l = l_part;
        l += __shfl_xor(l, 16);
        l += __shfl_xor(l, 32);
        const float inv = 1.0f / l;
        const int t = q0 + l15;
        #pragma unroll
        for (int dj = 0; dj < 4; ++dj) {
            uint2v w;
            w.x = cvt_pk_bf16(acc[dj][0] * inv, acc[dj][1] * inv);
            w.y = cvt_pk_bf16(acc[dj][2] * inv, acc[dj][3] * inv);
            *(uint2v*)&op[((size_t)(b * 2048 + t)) * 1024
                          + h * 64 + dj * 16 + l4 * 4] = w;
        }
    }
}

// ---------------------------------------------------------------------------
extern "C" void kernel_launch(void* const* d_in, const int* in_sizes, int n_in,
                              void* d_out, int out_size, void* d_ws, size_t ws_size,
                              hipStream_t stream)
{
    const float* q  = (const float*)d_in[0];
    const float* k  = (const float*)d_in[1];
    const float* v  = (const float*)d_in[2];
    const float* wq = (const float*)d_in[3];
    const float* bq = (const float*)d_in[4];
    const float* wk = (const float*)d_in[5];
    const float* bk = (const float*)d_in[6];
    const float* wv = (const float*)d_in[7];
    const float* bv = (const float*)d_in[8];
    const float* wo = (const float*)d_in[9];
    const float* bo = (const float*)d_in[10];
    float* out = (float*)d_out;

    const int M = 4096, N = 1024, K = 1024;
    unsigned char* ws = (unsigned char*)d_ws;
    const size_t SX = (size_t)M * K * 2;        // 8 MB
    const size_t SW = (size_t)N * K * 2;        // 2 MB
    unsigned short* xq  = (unsigned short*)(ws);
    unsigned short* xk  = (unsigned short*)(ws + SX);
    unsigned short* xv  = (unsigned short*)(ws + 2 * SX);
    unsigned short* wqb = (unsigned short*)(ws + 3 * SX);
    unsigned short* wkb = (unsigned short*)(ws + 3 * SX + SW);
    unsigned short* wvb = (unsigned short*)(ws + 3 * SX + 2 * SW);
    unsigned short* wob = (unsigned short*)(ws + 3 * SX + 3 * SW);
    unsigned short* qp  = (unsigned short*)(ws + 3 * SX + 4 * SW);
    unsigned short* kp  = qp + (size_t)M * N;
    unsigned short* vt  = kp + (size_t)M * N;
    unsigned short* opb = vt + (size_t)M * N;

    pack3_bf16<<<dim3(4096, 3), 256, 0, stream>>>(q, k, v, xq, xk, xv,
                                                  M * K / 4);
    pack4_bf16<<<dim3(1024, 4), 256, 0, stream>>>(wq, wk, wv, wo,
                                                  wqb, wkb, wvb, wob, N * K / 4);

    gemm_qkv<<<dim3(8, 32, 3), 256, 0, stream>>>(xq, xk, xv, wqb, wkb, wvb,
                                                 bq, bk, bv, qp, kp, vt);

    attn_fwd<<<dim3(512), 512, 0, stream>>>(qp, kp, vt, opb);

    gemm_out<<<dim3(8, 64), 256, 0, stream>>>(opb, wob, bo, out);
}

// Round 19
// 128.207 us; speedup vs baseline: 1.1187x; 1.0036x over previous
//
#include <hip/hip_runtime.h>
#include <math.h>

// ---------------------------------------------------------------------------
// MultiHeadAttention forward, MI355X/gfx950.  Round 19.
//   pack3/pack4: fp32 -> bf16 (frozen, HBM-roofline)
//   gemm_qkv: RETILED to gemm_out's proven structure (64x128 dbuf, 3
//     blocks/CU, T2 swizzle) with z-batch grid (8,64,3); gemm_out runs
//     ~860 TF-equiv vs old qkv ~680.
//   gemm_out: R13-exact
//   attn_fwd: R18 + max-shuffles hoisted INTO the rare rescale branch:
//     common path checks __all on lane-local maxima only (row max passes
//     iff all lane maxima pass; m_run only written under the branch, which
//     computes the full cross-lane max -> stays row-uniform).
// ---------------------------------------------------------------------------

typedef __attribute__((ext_vector_type(8))) short short8;     // 8 x bf16 frag
typedef __attribute__((ext_vector_type(4))) float f32x4;      // MFMA acc
typedef __attribute__((ext_vector_type(4))) float float4v;
typedef __attribute__((ext_vector_type(4))) unsigned short ushort4v;
typedef __attribute__((ext_vector_type(2))) unsigned int uint2v;

typedef __attribute__((address_space(3))) unsigned int lds_uint;
typedef __attribute__((address_space(1))) unsigned int glb_uint;

__device__ __forceinline__ void gload_lds16(const void* g, void* l) {
    __builtin_amdgcn_global_load_lds((glb_uint*)(unsigned long long)g,
                                     (lds_uint*)(unsigned int)(unsigned long long)l,
                                     16, 0, 0);
}

__device__ __forceinline__ unsigned short f32_bf16(float f) {
    union { float f; unsigned int u; } x; x.f = f;
    unsigned int r = x.u + 0x7fffu + ((x.u >> 16) & 1u);   // RNE
    return (unsigned short)(r >> 16);
}

__device__ __forceinline__ unsigned int cvt_pk_bf16(float lo, float hi) {
    unsigned int r;
    asm("v_cvt_pk_bf16_f32 %0, %1, %2" : "=v"(r) : "v"(lo), "v"(hi));
    return r;
}

// single-instruction exp2
__device__ __forceinline__ float exp2_fast(float x) {
    float r;
    asm("v_exp_f32 %0, %1" : "=v"(r) : "v"(x));
    return r;
}

// SCALE * log2(e): folded into Q projection so softmax runs in exp2 domain
#define QSCALE 0.18033688011112042f

// ---------------------------------------------------------------------------
__global__ void pack3_bf16(const float* __restrict__ a, const float* __restrict__ b,
                           const float* __restrict__ c,
                           unsigned short* __restrict__ oa, unsigned short* __restrict__ ob,
                           unsigned short* __restrict__ oc, int n4) {
    const int y = blockIdx.y;
    const float* in = (y == 0) ? a : (y == 1) ? b : c;
    unsigned short* out = (y == 0) ? oa : (y == 1) ? ob : oc;
    int i = blockIdx.x * blockDim.x + threadIdx.x;
    if (i < n4) {
        float4v v = ((const float4v*)in)[i];
        ushort4v o;
        o.x = f32_bf16(v.x); o.y = f32_bf16(v.y);
        o.z = f32_bf16(v.z); o.w = f32_bf16(v.w);
        ((ushort4v*)out)[i] = o;
    }
}

__global__ void pack4_bf16(const float* __restrict__ a, const float* __restrict__ b,
                           const float* __restrict__ c, const float* __restrict__ d,
                           unsigned short* __restrict__ oa, unsigned short* __restrict__ ob,
                           unsigned short* __restrict__ oc, unsigned short* __restrict__ od,
                           int n4) {
    const int y = blockIdx.y;
    const float* in = (y == 0) ? a : (y == 1) ? b : (y == 2) ? c : d;
    unsigned short* out = (y == 0) ? oa : (y == 1) ? ob : (y == 2) ? oc : od;
    int i = blockIdx.x * blockDim.x + threadIdx.x;
    if (i < n4) {
        float4v v = ((const float4v*)in)[i];
        ushort4v o;
        o.x = f32_bf16(v.x); o.y = f32_bf16(v.y);
        o.z = f32_bf16(v.z); o.w = f32_bf16(v.w);
        ((ushort4v*)out)[i] = o;
    }
}

// ---------------------------------------------------------------------------
// Batched QKV projection GEMM — gemm_out's proven 64x128 dbuf structure,
// z-batched: grid (8, 64, 3).  T2-swizzled LDS, 48KB -> 3 blocks/CU.
__global__ __launch_bounds__(256, 3) void gemm_qkv(
    const unsigned short* __restrict__ A0, const unsigned short* __restrict__ A1,
    const unsigned short* __restrict__ A2,
    const unsigned short* __restrict__ W0, const unsigned short* __restrict__ W1,
    const unsigned short* __restrict__ W2,
    const float* __restrict__ bs0, const float* __restrict__ bs1,
    const float* __restrict__ bs2,
    unsigned short* __restrict__ O0, unsigned short* __restrict__ O1,
    unsigned short* __restrict__ O2)
{
    const int z = blockIdx.z;
    const unsigned short* A = (z == 0) ? A0 : (z == 1) ? A1 : A2;
    const unsigned short* W = (z == 0) ? W0 : (z == 1) ? W1 : W2;
    const float* bias        = (z == 0) ? bs0 : (z == 1) ? bs1 : bs2;
    unsigned short* C        = (z == 0) ? O0 : (z == 1) ? O1 : O2;
    const float oscale = (z == 0) ? QSCALE : 1.0f;
    const int N = 1024, K = 1024;

    __shared__ unsigned short As[2][64 * 64];
    __shared__ unsigned short Bs[2][128 * 64];
    const int tid  = threadIdx.x;
    const int lane = tid & 63, wave = tid >> 6;
    const int l15 = lane & 15, l4 = lane >> 4;
    const int bm = blockIdx.y * 64, bn = blockIdx.x * 128;
    const int wr = wave >> 1, wc = wave & 1;
    const int swz = l15 & 7;

    f32x4 acc[2][4];
    #pragma unroll
    for (int i = 0; i < 2; ++i)
        #pragma unroll
        for (int j = 0; j < 4; ++j)
            #pragma unroll
            for (int e = 0; e < 4; ++e) acc[i][j][e] = 0.f;

    const int srow = lane >> 3;
    const int scol = ((lane & 7) ^ srow) * 8;

    auto stage = [&](int bf, int k0) {
        #pragma unroll
        for (int i = 0; i < 2; ++i) {
            const int c = wave * 2 + i;
            gload_lds16(A + (size_t)(bm + c * 8 + srow) * K + k0 + scol,
                        &As[bf][c * 512]);
        }
        #pragma unroll
        for (int i = 0; i < 4; ++i) {
            const int c = wave * 4 + i;
            gload_lds16(W + (size_t)(bn + c * 8 + srow) * K + k0 + scol,
                        &Bs[bf][c * 512]);
        }
    };

    stage(0, 0);
    __syncthreads();

    int bufi = 0;
    for (int k0 = 0; k0 < K; k0 += 64) {
        if (k0 + 64 < K) stage(bufi ^ 1, k0 + 64);
        #pragma unroll
        for (int kk = 0; kk < 2; ++kk) {
            short8 af[2], bf[4];
            const int ko = ((kk * 4 + l4) ^ swz) << 3;
            #pragma unroll
            for (int i = 0; i < 2; ++i)
                af[i] = *(const short8*)&As[bufi][(wr * 32 + i * 16 + l15) * 64 + ko];
            #pragma unroll
            for (int j = 0; j < 4; ++j)
                bf[j] = *(const short8*)&Bs[bufi][(wc * 64 + j * 16 + l15) * 64 + ko];
            #pragma unroll
            for (int i = 0; i < 2; ++i)
                #pragma unroll
                for (int j = 0; j < 4; ++j)
                    acc[i][j] = __builtin_amdgcn_mfma_f32_16x16x32_bf16(
                        af[i], bf[j], acc[i][j], 0, 0, 0);
        }
        __syncthreads();
        bufi ^= 1;
    }

    #pragma unroll
    for (int j = 0; j < 4; ++j) {
        const int col = bn + wc * 64 + j * 16 + l15;
        const float bj = bias[col];
        #pragma unroll
        for (int i = 0; i < 2; ++i) {
            const int row0 = bm + wr * 32 + i * 16 + l4 * 4;
            #pragma unroll
            for (int r = 0; r < 4; ++r) {
                const int row = row0 + r;
                const float v = (acc[i][j][r] + bj) * oscale;
                if (z < 2) {
                    C[(size_t)row * N + col] = f32_bf16(v);
                } else {
                    const int b = row >> 11, t = row & 2047;
                    C[(((size_t)((b << 4) + (col >> 6)) * 64
                        + (col & 63)) << 11) + t] = f32_bf16(v);
                }
            }
        }
    }
}

// ---------------------------------------------------------------------------
// Output-projection GEMM (fp32 out).  R13-exact: 64x128 dbuf + T2 swizzle.
__global__ __launch_bounds__(256, 3) void gemm_out(
    const unsigned short* __restrict__ A,
    const unsigned short* __restrict__ W,
    const float* __restrict__ bias,
    float* __restrict__ C)
{
    const int N = 1024, K = 1024;
    __shared__ unsigned short As[2][64 * 64];
    __shared__ unsigned short Bs[2][128 * 64];
    const int tid  = threadIdx.x;
    const int lane = tid & 63, wave = tid >> 6;
    const int l15 = lane & 15, l4 = lane >> 4;
    const int bm = blockIdx.y * 64, bn = blockIdx.x * 128;
    const int wr = wave >> 1, wc = wave & 1;
    const int swz = l15 & 7;

    f32x4 acc[2][4];
    #pragma unroll
    for (int i = 0; i < 2; ++i)
        #pragma unroll
        for (int j = 0; j < 4; ++j)
            #pragma unroll
            for (int e = 0; e < 4; ++e) acc[i][j][e] = 0.f;

    const int srow = lane >> 3;
    const int scol = ((lane & 7) ^ srow) * 8;

    auto stage = [&](int bf, int k0) {
        #pragma unroll
        for (int i = 0; i < 2; ++i) {
            const int c = wave * 2 + i;
            gload_lds16(A + (size_t)(bm + c * 8 + srow) * K + k0 + scol,
                        &As[bf][c * 512]);
        }
        #pragma unroll
        for (int i = 0; i < 4; ++i) {
            const int c = wave * 4 + i;
            gload_lds16(W + (size_t)(bn + c * 8 + srow) * K + k0 + scol,
                        &Bs[bf][c * 512]);
        }
    };

    stage(0, 0);
    __syncthreads();

    int bufi = 0;
    for (int k0 = 0; k0 < K; k0 += 64) {
        if (k0 + 64 < K) stage(bufi ^ 1, k0 + 64);
        #pragma unroll
        for (int kk = 0; kk < 2; ++kk) {
            short8 af[2], bf[4];
            const int ko = ((kk * 4 + l4) ^ swz) << 3;
            #pragma unroll
            for (int i = 0; i < 2; ++i)
                af[i] = *(const short8*)&As[bufi][(wr * 32 + i * 16 + l15) * 64 + ko];
            #pragma unroll
            for (int j = 0; j < 4; ++j)
                bf[j] = *(const short8*)&Bs[bufi][(wc * 64 + j * 16 + l15) * 64 + ko];
            #pragma unroll
            for (int i = 0; i < 2; ++i)
                #pragma unroll
                for (int j = 0; j < 4; ++j)
                    acc[i][j] = __builtin_amdgcn_mfma_f32_16x16x32_bf16(
                        af[i], bf[j], acc[i][j], 0, 0, 0);
        }
        __syncthreads();
        bufi ^= 1;
    }

    #pragma unroll
    for (int j = 0; j < 4; ++j) {
        const int col = bn + wc * 64 + j * 16 + l15;
        const float bj = bias[col];
        #pragma unroll
        for (int i = 0; i < 2; ++i) {
            const int row0 = bm + wr * 32 + i * 16 + l4 * 4;
            #pragma unroll
            for (int r = 0; r < 4; ++r)
                C[(size_t)(row0 + r) * N + col] = acc[i][j][r] + bj;
        }
    }
}

// ---------------------------------------------------------------------------
// Flash attention, R19 = R18 + max-shuffles moved into the rescale branch.
// Common path: lane-local max tree + __all check only (row max passes iff
// all 4 lanes of the row pass).  m_run written only under the branch (with
// the full cross-lane max) -> stays row-uniform.
__global__ __launch_bounds__(512, 4) void attn_fwd(
    const unsigned short* __restrict__ qp,
    const unsigned short* __restrict__ kp,
    const unsigned short* __restrict__ vt,
    unsigned short* __restrict__ op)
{
    __shared__ unsigned short Ks[2][128 * 64];  // [buf][kv 0..127][d] swizzled
    __shared__ unsigned short Vs[2][2][64 * 64];// [buf][half][d][kv]  swizzled
    __shared__ unsigned short P[8][16 * 64];    // [wave][q][kv]       swizzled

    const int tid = threadIdx.x;
    const int lane = tid & 63, wave = tid >> 6;  // wave 0..7
    const int l15 = lane & 15, l4 = lane >> 4;
    const int swz = (l15 & 7) << 3;             // XOR mask in short units

    // XCD-chunked block swizzle: 512 blocks, bijective (512%8==0)
    const int flat = blockIdx.x;
    const int swzb = (flat & 7) * 64 + (flat >> 3);
    const int bx = swzb & 15;                   // q-tile index (128 rows)
    const int bh = swzb >> 4;                   // batch*head
    const int b = bh >> 4, h = bh & 15;
    const int q0 = bx * 128 + wave * 16;

    const size_t xbase = (size_t)b * 2048 * 1024 + h * 64;   // qp/kp
    const size_t vbase = (size_t)bh * 64 * 2048;             // vt

    // staging source addressing (pre-swizzled global col, m173 pattern)
    const int sr = lane >> 3;                   // row within 8-row chunk
    const int sc = ((lane & 7) ^ sr) * 8;       // swizzled col (shorts)

    // Q as B-operand frags: col=q(l15), k=d
    short8 bq[2];
    #pragma unroll
    for (int kk = 0; kk < 2; ++kk)
        bq[kk] = *(const short8*)&qp[xbase
            + (size_t)(q0 + l15) * 1024 + kk * 32 + l4 * 8];

    f32x4 acc[4];                   // O^T: [dj]; row=d_local, col=q=l15
    #pragma unroll
    for (int dj = 0; dj < 4; ++dj)
        #pragma unroll
        for (int e = 0; e < 4; ++e) acc[dj][e] = 0.f;

    float m_run = -1e30f, l_part = 0.f;         // l lane-partial (16 kv/lane)

    // staging: K = 16 chunks (2/wave), V = 2 halves x 8 chunks (2/wave total)
    auto stage = [&](int bf, int kv0) {
        #pragma unroll
        for (int i = 0; i < 2; ++i) {
            const int c = wave * 2 + i;
            gload_lds16(kp + xbase + (size_t)(kv0 + c * 8 + sr) * 1024 + sc,
                        &Ks[bf][c * 512]);
        }
        #pragma unroll
        for (int h2 = 0; h2 < 2; ++h2)
            gload_lds16(vt + vbase + (size_t)(wave * 8 + sr) * 2048
                            + kv0 + h2 * 64 + sc,
                        &Vs[bf][h2][wave * 512]);
    };

    // ---- prologue: stage tile 0 into buf 0 ----
    stage(0, 0);
    __syncthreads();

    const int NT = 2048 / 128;
    int buf = 0;
    for (int t = 0; t < NT; ++t) {
        // ---- stage next 128-kv tile into buf^1 ----
        if (t + 1 < NT) stage(buf ^ 1, (t + 1) * 128);

        #pragma unroll
        for (int hh = 0; hh < 2; ++hh) {
            // ---- S^T = K Q^T for this 64-kv half ----
            f32x4 st[4];            // kv = hh*64 + j*16 + l4*4 + r ; q = l15
            {
                short8 ak[4];
                #pragma unroll
                for (int j = 0; j < 4; ++j)
                    ak[j] = *(const short8*)&Ks[buf][(hh * 64 + j * 16 + l15) * 64
                                                     + ((l4 << 3) ^ swz)];
                const f32x4 z4 = {0.f, 0.f, 0.f, 0.f};
                #pragma unroll
                for (int j = 0; j < 4; ++j)
                    st[j] = __builtin_amdgcn_mfma_f32_16x16x32_bf16(
                        ak[j], bq[0], z4, 0, 0, 0);
                #pragma unroll
                for (int j = 0; j < 4; ++j)
                    ak[j] = *(const short8*)&Ks[buf][(hh * 64 + j * 16 + l15) * 64
                                                     + (((4 + l4) << 3) ^ swz)];
                #pragma unroll
                for (int j = 0; j < 4; ++j)
                    st[j] = __builtin_amdgcn_mfma_f32_16x16x32_bf16(
                        ak[j], bq[1], st[j], 0, 0, 0);
            }

            // ---- prefetch V frags for this half ----
            short8 av[2][4];        // [kvc][dj]
            #pragma unroll
            for (int kvc = 0; kvc < 2; ++kvc)
                #pragma unroll
                for (int dj = 0; dj < 4; ++dj)
                    av[kvc][dj] = *(const short8*)&Vs[buf][hh]
                        [(dj * 16 + l15) * 64 + (((kvc * 4 + l4) << 3) ^ swz)];

            // ---- softmax (exp2 domain), defer-max, branch-local shuffles ----
            {
                float tm[4];
                #pragma unroll
                for (int j = 0; j < 4; ++j)
                    tm[j] = fmaxf(fmaxf(st[j][0], st[j][1]),
                                  fmaxf(st[j][2], st[j][3]));
                const float mxl = fmaxf(fmaxf(tm[0], tm[1]),
                                        fmaxf(tm[2], tm[3]));   // lane-local
                // row max <= m_run+8  iff  all 4 lanes' local maxima pass
                if (!__all(mxl - m_run <= 8.0f)) {
                    float mx = fmaxf(mxl, __shfl_xor(mxl, 16));
                    mx = fmaxf(mx, __shfl_xor(mx, 32));
                    const float mnew = fmaxf(m_run, mx);
                    const float corr = exp2_fast(m_run - mnew);
                    m_run = mnew;
                    l_part *= corr;
                    #pragma unroll
                    for (int dj = 0; dj < 4; ++dj) acc[dj] *= corr;
                }
                float ts[4];
                #pragma unroll
                for (int j = 0; j < 4; ++j) {
                    float p0 = exp2_fast(st[j][0] - m_run);
                    float p1 = exp2_fast(st[j][1] - m_run);
                    float p2 = exp2_fast(st[j][2] - m_run);
                    float p3 = exp2_fast(st[j][3] - m_run);
                    st[j][0] = p0; st[j][1] = p1;
                    st[j][2] = p2; st[j][3] = p3;
                    ts[j] = (p0 + p1) + (p2 + p3);
                }
                l_part += (ts[0] + ts[1]) + (ts[2] + ts[3]);
            }

            // ---- P^T -> swizzled per-wave LDS (b64 writes) ----
            #pragma unroll
            for (int j = 0; j < 4; ++j) {
                uint2v w;
                w.x = cvt_pk_bf16(st[j][0], st[j][1]);
                w.y = cvt_pk_bf16(st[j][2], st[j][3]);
                *(uint2v*)&P[wave][l15 * 64 + ((j * 16 + l4 * 4) ^ swz)] = w;
            }

            // ---- O^T += V^T P^T ----
            #pragma unroll
            for (int kvc = 0; kvc < 2; ++kvc) {
                short8 pb = *(const short8*)&P[wave][l15 * 64
                                                + (((kvc * 4 + l4) << 3) ^ swz)];
                #pragma unroll
                for (int dj = 0; dj < 4; ++dj)
                    acc[dj] = __builtin_amdgcn_mfma_f32_16x16x32_bf16(
                        av[kvc][dj], pb, acc[dj], 0, 0, 0);
            }
        }

        __syncthreads();            // drains vmcnt (staging done) + LDS reads
        buf ^= 1;
    }

    // ---- epilogue: reduce lane-partial l, divide, 8B vector stores ----
    {
        float l = l_part;
        l += __shfl_xor(l, 16);
        l += __shfl_xor(l, 32);
        const float inv = 1.0f / l;
        const int t = q0 + l15;
        #pragma unroll
        for (int dj = 0; dj < 4; ++dj) {
            uint2v w;
            w.x = cvt_pk_bf16(acc[dj][0] * inv, acc[dj][1] * inv);
            w.y = cvt_pk_bf16(acc[dj][2] * inv, acc[dj][3] * inv);
            *(uint2v*)&op[((size_t)(b * 2048 + t)) * 1024
                          + h * 64 + dj * 16 + l4 * 4] = w;
        }
    }
}

// ---------------------------------------------------------------------------
extern "C" void kernel_launch(void* const* d_in, const int* in_sizes, int n_in,
                              void* d_out, int out_size, void* d_ws, size_t ws_size,
                              hipStream_t stream)
{
    const float* q  = (const float*)d_in[0];
    const float* k  = (const float*)d_in[1];
    const float* v  = (const float*)d_in[2];
    const float* wq = (const float*)d_in[3];
    const float* bq = (const float*)d_in[4];
    const float* wk = (const float*)d_in[5];
    const float* bk = (const float*)d_in[6];
    const float* wv = (const float*)d_in[7];
    const float* bv = (const float*)d_in[8];
    const float* wo = (const float*)d_in[9];
    const float* bo = (const float*)d_in[10];
    float* out = (float*)d_out;

    const int M = 4096, N = 1024, K = 1024;
    unsigned char* ws = (unsigned char*)d_ws;
    const size_t SX = (size_t)M * K * 2;        // 8 MB
    const size_t SW = (size_t)N * K * 2;        // 2 MB
    unsigned short* xq  = (unsigned short*)(ws);
    unsigned short* xk  = (unsigned short*)(ws + SX);
    unsigned short* xv  = (unsigned short*)(ws + 2 * SX);
    unsigned short* wqb = (unsigned short*)(ws + 3 * SX);
    unsigned short* wkb = (unsigned short*)(ws + 3 * SX + SW);
    unsigned short* wvb = (unsigned short*)(ws + 3 * SX + 2 * SW);
    unsigned short* wob = (unsigned short*)(ws + 3 * SX + 3 * SW);
    unsigned short* qp  = (unsigned short*)(ws + 3 * SX + 4 * SW);
    unsigned short* kp  = qp + (size_t)M * N;
    unsigned short* vt  = kp + (size_t)M * N;
    unsigned short* opb = vt + (size_t)M * N;

    pack3_bf16<<<dim3(4096, 3), 256, 0, stream>>>(q, k, v, xq, xk, xv,
                                                  M * K / 4);
    pack4_bf16<<<dim3(1024, 4), 256, 0, stream>>>(wq, wk, wv, wo,
                                                  wqb, wkb, wvb, wob, N * K / 4);

    gemm_qkv<<<dim3(8, 64, 3), 256, 0, stream>>>(xq, xk, xv, wqb, wkb, wvb,
                                                 bq, bk, bv, qp, kp, vt);

    attn_fwd<<<dim3(512), 512, 0, stream>>>(qp, kp, vt, opb);

    gemm_out<<<dim3(8, 64), 256, 0, stream>>>(opb, wob, bo, out);
}

// Round 20
// 126.324 us; speedup vs baseline: 1.1354x; 1.0149x over previous
//
#include <hip/hip_runtime.h>
#include <math.h>

// ---------------------------------------------------------------------------
// MultiHeadAttention forward, MI355X/gfx950.  Round 20.
//   pack3/pack4: fp32 -> bf16 (frozen, HBM-roofline)
//   gemm_qkv: REVERTED to R13-exact 128x128 (256,2) + T2 swizzle — R19's
//     64x128 retile cost +2.7us (doubled W-panel re-reads: 64 M-blocks vs 32)
//   gemm_out: R13-exact (64x128 dbuf + T2 swizzle)
//   attn_fwd: R19-exact (best: 58.1us, defer-max + branch-local shuffles)
// ---------------------------------------------------------------------------

typedef __attribute__((ext_vector_type(8))) short short8;     // 8 x bf16 frag
typedef __attribute__((ext_vector_type(4))) float f32x4;      // MFMA acc
typedef __attribute__((ext_vector_type(4))) float float4v;
typedef __attribute__((ext_vector_type(4))) unsigned short ushort4v;
typedef __attribute__((ext_vector_type(2))) unsigned int uint2v;

typedef __attribute__((address_space(3))) unsigned int lds_uint;
typedef __attribute__((address_space(1))) unsigned int glb_uint;

__device__ __forceinline__ void gload_lds16(const void* g, void* l) {
    __builtin_amdgcn_global_load_lds((glb_uint*)(unsigned long long)g,
                                     (lds_uint*)(unsigned int)(unsigned long long)l,
                                     16, 0, 0);
}

__device__ __forceinline__ unsigned short f32_bf16(float f) {
    union { float f; unsigned int u; } x; x.f = f;
    unsigned int r = x.u + 0x7fffu + ((x.u >> 16) & 1u);   // RNE
    return (unsigned short)(r >> 16);
}

__device__ __forceinline__ unsigned int cvt_pk_bf16(float lo, float hi) {
    unsigned int r;
    asm("v_cvt_pk_bf16_f32 %0, %1, %2" : "=v"(r) : "v"(lo), "v"(hi));
    return r;
}

// single-instruction exp2
__device__ __forceinline__ float exp2_fast(float x) {
    float r;
    asm("v_exp_f32 %0, %1" : "=v"(r) : "v"(x));
    return r;
}

// SCALE * log2(e): folded into Q projection so softmax runs in exp2 domain
#define QSCALE 0.18033688011112042f

// ---------------------------------------------------------------------------
__global__ void pack3_bf16(const float* __restrict__ a, const float* __restrict__ b,
                           const float* __restrict__ c,
                           unsigned short* __restrict__ oa, unsigned short* __restrict__ ob,
                           unsigned short* __restrict__ oc, int n4) {
    const int y = blockIdx.y;
    const float* in = (y == 0) ? a : (y == 1) ? b : c;
    unsigned short* out = (y == 0) ? oa : (y == 1) ? ob : oc;
    int i = blockIdx.x * blockDim.x + threadIdx.x;
    if (i < n4) {
        float4v v = ((const float4v*)in)[i];
        ushort4v o;
        o.x = f32_bf16(v.x); o.y = f32_bf16(v.y);
        o.z = f32_bf16(v.z); o.w = f32_bf16(v.w);
        ((ushort4v*)out)[i] = o;
    }
}

__global__ void pack4_bf16(const float* __restrict__ a, const float* __restrict__ b,
                           const float* __restrict__ c, const float* __restrict__ d,
                           unsigned short* __restrict__ oa, unsigned short* __restrict__ ob,
                           unsigned short* __restrict__ oc, unsigned short* __restrict__ od,
                           int n4) {
    const int y = blockIdx.y;
    const float* in = (y == 0) ? a : (y == 1) ? b : (y == 2) ? c : d;
    unsigned short* out = (y == 0) ? oa : (y == 1) ? ob : (y == 2) ? oc : od;
    int i = blockIdx.x * blockDim.x + threadIdx.x;
    if (i < n4) {
        float4v v = ((const float4v*)in)[i];
        ushort4v o;
        o.x = f32_bf16(v.x); o.y = f32_bf16(v.y);
        o.z = f32_bf16(v.z); o.w = f32_bf16(v.w);
        ((ushort4v*)out)[i] = o;
    }
}

// ---------------------------------------------------------------------------
// Batched QKV projection GEMM (R13-exact: 128x128, 4 waves, T2 swizzle).
__global__ __launch_bounds__(256, 2) void gemm_qkv(
    const unsigned short* __restrict__ A0, const unsigned short* __restrict__ A1,
    const unsigned short* __restrict__ A2,
    const unsigned short* __restrict__ W0, const unsigned short* __restrict__ W1,
    const unsigned short* __restrict__ W2,
    const float* __restrict__ bs0, const float* __restrict__ bs1,
    const float* __restrict__ bs2,
    unsigned short* __restrict__ O0, unsigned short* __restrict__ O1,
    unsigned short* __restrict__ O2)
{
    const int z = blockIdx.z;
    const unsigned short* A = (z == 0) ? A0 : (z == 1) ? A1 : A2;
    const unsigned short* W = (z == 0) ? W0 : (z == 1) ? W1 : W2;
    const float* bias        = (z == 0) ? bs0 : (z == 1) ? bs1 : bs2;
    unsigned short* C        = (z == 0) ? O0 : (z == 1) ? O1 : O2;
    const float oscale = (z == 0) ? QSCALE : 1.0f;
    const int N = 1024, K = 1024;

    __shared__ unsigned short As[128 * 64];
    __shared__ unsigned short Bs[128 * 64];
    const int tid  = threadIdx.x;
    const int lane = tid & 63, wave = tid >> 6;
    const int l15 = lane & 15, l4 = lane >> 4;
    const int bm = blockIdx.y * 128, bn = blockIdx.x * 128;
    const int wr = wave >> 1, wc = wave & 1;
    const int swz = l15 & 7;                    // XOR key (8-short units)

    f32x4 acc[4][4];
    #pragma unroll
    for (int i = 0; i < 4; ++i)
        #pragma unroll
        for (int j = 0; j < 4; ++j)
            #pragma unroll
            for (int e = 0; e < 4; ++e) acc[i][j][e] = 0.f;

    const int srow = lane >> 3;                 // row 0..7 within chunk
    const int scol = ((lane & 7) ^ srow) * 8;   // pre-swizzled source col

    for (int k0 = 0; k0 < K; k0 += 64) {
        __syncthreads();
        #pragma unroll
        for (int i = 0; i < 4; ++i) {
            int c = wave * 4 + i;
            int row = c * 8 + srow;
            gload_lds16(A + (size_t)(bm + row) * K + k0 + scol, &As[c * 512]);
            gload_lds16(W + (size_t)(bn + row) * K + k0 + scol, &Bs[c * 512]);
        }
        __syncthreads();
        #pragma unroll
        for (int kk = 0; kk < 2; ++kk) {
            short8 af[4], bf[4];
            const int ko = ((kk * 4 + l4) ^ swz) << 3;   // swizzled col
            #pragma unroll
            for (int i = 0; i < 4; ++i)
                af[i] = *(const short8*)&As[(wr * 64 + i * 16 + l15) * 64 + ko];
            #pragma unroll
            for (int j = 0; j < 4; ++j)
                bf[j] = *(const short8*)&Bs[(wc * 64 + j * 16 + l15) * 64 + ko];
            #pragma unroll
            for (int i = 0; i < 4; ++i)
                #pragma unroll
                for (int j = 0; j < 4; ++j)
                    acc[i][j] = __builtin_amdgcn_mfma_f32_16x16x32_bf16(
                        af[i], bf[j], acc[i][j], 0, 0, 0);
        }
    }

    #pragma unroll
    for (int j = 0; j < 4; ++j) {
        const int col = bn + wc * 64 + j * 16 + l15;
        const float bj = bias[col];
        #pragma unroll
        for (int i = 0; i < 4; ++i) {
            const int row0 = bm + wr * 64 + i * 16 + l4 * 4;
            #pragma unroll
            for (int r = 0; r < 4; ++r) {
                const int row = row0 + r;
                const float v = (acc[i][j][r] + bj) * oscale;
                if (z < 2) {
                    C[(size_t)row * N + col] = f32_bf16(v);
                } else {
                    const int b = row >> 11, t = row & 2047;
                    C[(((size_t)((b << 4) + (col >> 6)) * 64
                        + (col & 63)) << 11) + t] = f32_bf16(v);
                }
            }
        }
    }
}

// ---------------------------------------------------------------------------
// Output-projection GEMM (fp32 out).  R13-exact: 64x128 dbuf + T2 swizzle.
__global__ __launch_bounds__(256, 3) void gemm_out(
    const unsigned short* __restrict__ A,
    const unsigned short* __restrict__ W,
    const float* __restrict__ bias,
    float* __restrict__ C)
{
    const int N = 1024, K = 1024;
    __shared__ unsigned short As[2][64 * 64];
    __shared__ unsigned short Bs[2][128 * 64];
    const int tid  = threadIdx.x;
    const int lane = tid & 63, wave = tid >> 6;
    const int l15 = lane & 15, l4 = lane >> 4;
    const int bm = blockIdx.y * 64, bn = blockIdx.x * 128;
    const int wr = wave >> 1, wc = wave & 1;
    const int swz = l15 & 7;

    f32x4 acc[2][4];
    #pragma unroll
    for (int i = 0; i < 2; ++i)
        #pragma unroll
        for (int j = 0; j < 4; ++j)
            #pragma unroll
            for (int e = 0; e < 4; ++e) acc[i][j][e] = 0.f;

    const int srow = lane >> 3;
    const int scol = ((lane & 7) ^ srow) * 8;

    auto stage = [&](int bf, int k0) {
        #pragma unroll
        for (int i = 0; i < 2; ++i) {
            const int c = wave * 2 + i;
            gload_lds16(A + (size_t)(bm + c * 8 + srow) * K + k0 + scol,
                        &As[bf][c * 512]);
        }
        #pragma unroll
        for (int i = 0; i < 4; ++i) {
            const int c = wave * 4 + i;
            gload_lds16(W + (size_t)(bn + c * 8 + srow) * K + k0 + scol,
                        &Bs[bf][c * 512]);
        }
    };

    stage(0, 0);
    __syncthreads();

    int bufi = 0;
    for (int k0 = 0; k0 < K; k0 += 64) {
        if (k0 + 64 < K) stage(bufi ^ 1, k0 + 64);
        #pragma unroll
        for (int kk = 0; kk < 2; ++kk) {
            short8 af[2], bf[4];
            const int ko = ((kk * 4 + l4) ^ swz) << 3;
            #pragma unroll
            for (int i = 0; i < 2; ++i)
                af[i] = *(const short8*)&As[bufi][(wr * 32 + i * 16 + l15) * 64 + ko];
            #pragma unroll
            for (int j = 0; j < 4; ++j)
                bf[j] = *(const short8*)&Bs[bufi][(wc * 64 + j * 16 + l15) * 64 + ko];
            #pragma unroll
            for (int i = 0; i < 2; ++i)
                #pragma unroll
                for (int j = 0; j < 4; ++j)
                    acc[i][j] = __builtin_amdgcn_mfma_f32_16x16x32_bf16(
                        af[i], bf[j], acc[i][j], 0, 0, 0);
        }
        __syncthreads();
        bufi ^= 1;
    }

    #pragma unroll
    for (int j = 0; j < 4; ++j) {
        const int col = bn + wc * 64 + j * 16 + l15;
        const float bj = bias[col];
        #pragma unroll
        for (int i = 0; i < 2; ++i) {
            const int row0 = bm + wr * 32 + i * 16 + l4 * 4;
            #pragma unroll
            for (int r = 0; r < 4; ++r)
                C[(size_t)(row0 + r) * N + col] = acc[i][j][r] + bj;
        }
    }
}

// ---------------------------------------------------------------------------
// Flash attention, R19-exact (best: 58.1us).  defer-max + branch-local
// shuffles; 8 waves, KVBLK=128 dbuf as two 64-halves, XCD-chunked.
__global__ __launch_bounds__(512, 4) void attn_fwd(
    const unsigned short* __restrict__ qp,
    const unsigned short* __restrict__ kp,
    const unsigned short* __restrict__ vt,
    unsigned short* __restrict__ op)
{
    __shared__ unsigned short Ks[2][128 * 64];  // [buf][kv 0..127][d] swizzled
    __shared__ unsigned short Vs[2][2][64 * 64];// [buf][half][d][kv]  swizzled
    __shared__ unsigned short P[8][16 * 64];    // [wave][q][kv]       swizzled

    const int tid = threadIdx.x;
    const int lane = tid & 63, wave = tid >> 6;  // wave 0..7
    const int l15 = lane & 15, l4 = lane >> 4;
    const int swz = (l15 & 7) << 3;             // XOR mask in short units

    // XCD-chunked block swizzle: 512 blocks, bijective (512%8==0)
    const int flat = blockIdx.x;
    const int swzb = (flat & 7) * 64 + (flat >> 3);
    const int bx = swzb & 15;                   // q-tile index (128 rows)
    const int bh = swzb >> 4;                   // batch*head
    const int b = bh >> 4, h = bh & 15;
    const int q0 = bx * 128 + wave * 16;

    const size_t xbase = (size_t)b * 2048 * 1024 + h * 64;   // qp/kp
    const size_t vbase = (size_t)bh * 64 * 2048;             // vt

    // staging source addressing (pre-swizzled global col, m173 pattern)
    const int sr = lane >> 3;                   // row within 8-row chunk
    const int sc = ((lane & 7) ^ sr) * 8;       // swizzled col (shorts)

    // Q as B-operand frags: col=q(l15), k=d
    short8 bq[2];
    #pragma unroll
    for (int kk = 0; kk < 2; ++kk)
        bq[kk] = *(const short8*)&qp[xbase
            + (size_t)(q0 + l15) * 1024 + kk * 32 + l4 * 8];

    f32x4 acc[4];                   // O^T: [dj]; row=d_local, col=q=l15
    #pragma unroll
    for (int dj = 0; dj < 4; ++dj)
        #pragma unroll
        for (int e = 0; e < 4; ++e) acc[dj][e] = 0.f;

    float m_run = -1e30f, l_part = 0.f;         // l lane-partial (16 kv/lane)

    // staging: K = 16 chunks (2/wave), V = 2 halves x 8 chunks (2/wave total)
    auto stage = [&](int bf, int kv0) {
        #pragma unroll
        for (int i = 0; i < 2; ++i) {
            const int c = wave * 2 + i;
            gload_lds16(kp + xbase + (size_t)(kv0 + c * 8 + sr) * 1024 + sc,
                        &Ks[bf][c * 512]);
        }
        #pragma unroll
        for (int h2 = 0; h2 < 2; ++h2)
            gload_lds16(vt + vbase + (size_t)(wave * 8 + sr) * 2048
                            + kv0 + h2 * 64 + sc,
                        &Vs[bf][h2][wave * 512]);
    };

    // ---- prologue: stage tile 0 into buf 0 ----
    stage(0, 0);
    __syncthreads();

    const int NT = 2048 / 128;
    int buf = 0;
    for (int t = 0; t < NT; ++t) {
        // ---- stage next 128-kv tile into buf^1 ----
        if (t + 1 < NT) stage(buf ^ 1, (t + 1) * 128);

        #pragma unroll
        for (int hh = 0; hh < 2; ++hh) {
            // ---- S^T = K Q^T for this 64-kv half ----
            f32x4 st[4];            // kv = hh*64 + j*16 + l4*4 + r ; q = l15
            {
                short8 ak[4];
                #pragma unroll
                for (int j = 0; j < 4; ++j)
                    ak[j] = *(const short8*)&Ks[buf][(hh * 64 + j * 16 + l15) * 64
                                                     + ((l4 << 3) ^ swz)];
                const f32x4 z4 = {0.f, 0.f, 0.f, 0.f};
                #pragma unroll
                for (int j = 0; j < 4; ++j)
                    st[j] = __builtin_amdgcn_mfma_f32_16x16x32_bf16(
                        ak[j], bq[0], z4, 0, 0, 0);
                #pragma unroll
                for (int j = 0; j < 4; ++j)
                    ak[j] = *(const short8*)&Ks[buf][(hh * 64 + j * 16 + l15) * 64
                                                     + (((4 + l4) << 3) ^ swz)];
                #pragma unroll
                for (int j = 0; j < 4; ++j)
                    st[j] = __builtin_amdgcn_mfma_f32_16x16x32_bf16(
                        ak[j], bq[1], st[j], 0, 0, 0);
            }

            // ---- prefetch V frags for this half ----
            short8 av[2][4];        // [kvc][dj]
            #pragma unroll
            for (int kvc = 0; kvc < 2; ++kvc)
                #pragma unroll
                for (int dj = 0; dj < 4; ++dj)
                    av[kvc][dj] = *(const short8*)&Vs[buf][hh]
                        [(dj * 16 + l15) * 64 + (((kvc * 4 + l4) << 3) ^ swz)];

            // ---- softmax (exp2 domain), defer-max, branch-local shuffles ----
            {
                float tm[4];
                #pragma unroll
                for (int j = 0; j < 4; ++j)
                    tm[j] = fmaxf(fmaxf(st[j][0], st[j][1]),
                                  fmaxf(st[j][2], st[j][3]));
                const float mxl = fmaxf(fmaxf(tm[0], tm[1]),
                                        fmaxf(tm[2], tm[3]));   // lane-local
                // row max <= m_run+8  iff  all 4 lanes' local maxima pass
                if (!__all(mxl - m_run <= 8.0f)) {
                    float mx = fmaxf(mxl, __shfl_xor(mxl, 16));
                    mx = fmaxf(mx, __shfl_xor(mx, 32));
                    const float mnew = fmaxf(m_run, mx);
                    const float corr = exp2_fast(m_run - mnew);
                    m_run = mnew;
                    l_part *= corr;
                    #pragma unroll
                    for (int dj = 0; dj < 4; ++dj) acc[dj] *= corr;
                }
                float ts[4];
                #pragma unroll
                for (int j = 0; j < 4; ++j) {
                    float p0 = exp2_fast(st[j][0] - m_run);
                    float p1 = exp2_fast(st[j][1] - m_run);
                    float p2 = exp2_fast(st[j][2] - m_run);
                    float p3 = exp2_fast(st[j][3] - m_run);
                    st[j][0] = p0; st[j][1] = p1;
                    st[j][2] = p2; st[j][3] = p3;
                    ts[j] = (p0 + p1) + (p2 + p3);
                }
                l_part += (ts[0] + ts[1]) + (ts[2] + ts[3]);
            }

            // ---- P^T -> swizzled per-wave LDS (b64 writes) ----
            #pragma unroll
            for (int j = 0; j < 4; ++j) {
                uint2v w;
                w.x = cvt_pk_bf16(st[j][0], st[j][1]);
                w.y = cvt_pk_bf16(st[j][2], st[j][3]);
                *(uint2v*)&P[wave][l15 * 64 + ((j * 16 + l4 * 4) ^ swz)] = w;
            }

            // ---- O^T += V^T P^T ----
            #pragma unroll
            for (int kvc = 0; kvc < 2; ++kvc) {
                short8 pb = *(const short8*)&P[wave][l15 * 64
                                                + (((kvc * 4 + l4) << 3) ^ swz)];
                #pragma unroll
                for (int dj = 0; dj < 4; ++dj)
                    acc[dj] = __builtin_amdgcn_mfma_f32_16x16x32_bf16(
                        av[kvc][dj], pb, acc[dj], 0, 0, 0);
            }
        }

        __syncthreads();            // drains vmcnt (staging done) + LDS reads
        buf ^= 1;
    }

    // ---- epilogue: reduce lane-partial l, divide, 8B vector stores ----
    {
        float l = l_part;
        l += __shfl_xor(l, 16);
        l += __shfl_xor(l, 32);
        const float inv = 1.0f / l;
        const int t = q0 + l15;
        #pragma unroll
        for (int dj = 0; dj < 4; ++dj) {
            uint2v w;
            w.x = cvt_pk_bf16(acc[dj][0] * inv, acc[dj][1] * inv);
            w.y = cvt_pk_bf16(acc[dj][2] * inv, acc[dj][3] * inv);
            *(uint2v*)&op[((size_t)(b * 2048 + t)) * 1024
                          + h * 64 + dj * 16 + l4 * 4] = w;
        }
    }
}

// ---------------------------------------------------------------------------
extern "C" void kernel_launch(void* const* d_in, const int* in_sizes, int n_in,
                              void* d_out, int out_size, void* d_ws, size_t ws_size,
                              hipStream_t stream)
{
    const float* q  = (const float*)d_in[0];
    const float* k  = (const float*)d_in[1];
    const float* v  = (const float*)d_in[2];
    const float* wq = (const float*)d_in[3];
    const float* bq = (const float*)d_in[4];
    const float* wk = (const float*)d_in[5];
    const float* bk = (const float*)d_in[6];
    const float* wv = (const float*)d_in[7];
    const float* bv = (const float*)d_in[8];
    const float* wo = (const float*)d_in[9];
    const float* bo = (const float*)d_in[10];
    float* out = (float*)d_out;

    const int M = 4096, N = 1024, K = 1024;
    unsigned char* ws = (unsigned char*)d_ws;
    const size_t SX = (size_t)M * K * 2;        // 8 MB
    const size_t SW = (size_t)N * K * 2;        // 2 MB
    unsigned short* xq  = (unsigned short*)(ws);
    unsigned short* xk  = (unsigned short*)(ws + SX);
    unsigned short* xv  = (unsigned short*)(ws + 2 * SX);
    unsigned short* wqb = (unsigned short*)(ws + 3 * SX);
    unsigned short* wkb = (unsigned short*)(ws + 3 * SX + SW);
    unsigned short* wvb = (unsigned short*)(ws + 3 * SX + 2 * SW);
    unsigned short* wob = (unsigned short*)(ws + 3 * SX + 3 * SW);
    unsigned short* qp  = (unsigned short*)(ws + 3 * SX + 4 * SW);
    unsigned short* kp  = qp + (size_t)M * N;
    unsigned short* vt  = kp + (size_t)M * N;
    unsigned short* opb = vt + (size_t)M * N;

    pack3_bf16<<<dim3(4096, 3), 256, 0, stream>>>(q, k, v, xq, xk, xv,
                                                  M * K / 4);
    pack4_bf16<<<dim3(1024, 4), 256, 0, stream>>>(wq, wk, wv, wo,
                                                  wqb, wkb, wvb, wob, N * K / 4);

    gemm_qkv<<<dim3(8, 32, 3), 256, 0, stream>>>(xq, xk, xv, wqb, wkb, wvb,
                                                 bq, bk, bv, qp, kp, vt);

    attn_fwd<<<dim3(512), 512, 0, stream>>>(qp, kp, vt, opb);

    gemm_out<<<dim3(8, 64), 256, 0, stream>>>(opb, wob, bo, out);
}

// Round 21
// 124.656 us; speedup vs baseline: 1.1506x; 1.0134x over previous
//
#include <hip/hip_runtime.h>
#include <math.h>

// ---------------------------------------------------------------------------
// MultiHeadAttention forward, MI355X/gfx950.  Round 21 (final form).
//   pack_all: SINGLE fused fp32->bf16 pack (q/k/v + 4 weights, one launch)
//   gemm_qkv: R13-exact 128x128 (256,2) + T2 swizzle (measured best)
//   gemm_out: R13-exact 64x128 dbuf + T2 swizzle
//   attn_fwd: R19-exact (58.1us: defer-max + branch-local shuffles,
//             8 waves, KVBLK=128 dbuf as two 64-halves, XCD-chunked)
// ---------------------------------------------------------------------------

typedef __attribute__((ext_vector_type(8))) short short8;     // 8 x bf16 frag
typedef __attribute__((ext_vector_type(4))) float f32x4;      // MFMA acc
typedef __attribute__((ext_vector_type(4))) float float4v;
typedef __attribute__((ext_vector_type(4))) unsigned short ushort4v;
typedef __attribute__((ext_vector_type(2))) unsigned int uint2v;

typedef __attribute__((address_space(3))) unsigned int lds_uint;
typedef __attribute__((address_space(1))) unsigned int glb_uint;

__device__ __forceinline__ void gload_lds16(const void* g, void* l) {
    __builtin_amdgcn_global_load_lds((glb_uint*)(unsigned long long)g,
                                     (lds_uint*)(unsigned int)(unsigned long long)l,
                                     16, 0, 0);
}

__device__ __forceinline__ unsigned short f32_bf16(float f) {
    union { float f; unsigned int u; } x; x.f = f;
    unsigned int r = x.u + 0x7fffu + ((x.u >> 16) & 1u);   // RNE
    return (unsigned short)(r >> 16);
}

__device__ __forceinline__ unsigned int cvt_pk_bf16(float lo, float hi) {
    unsigned int r;
    asm("v_cvt_pk_bf16_f32 %0, %1, %2" : "=v"(r) : "v"(lo), "v"(hi));
    return r;
}

// single-instruction exp2
__device__ __forceinline__ float exp2_fast(float x) {
    float r;
    asm("v_exp_f32 %0, %1" : "=v"(r) : "v"(x));
    return r;
}

// SCALE * log2(e): folded into Q projection so softmax runs in exp2 domain
#define QSCALE 0.18033688011112042f

// ---------------------------------------------------------------------------
// Fused pack: blocks 0..12287 -> q/k/v (4096 blocks each, 1M f32x4 each);
// blocks 12288..16383 -> wq/wk/wv/wo (1024 blocks each, 256K f32x4 each).
__global__ void pack_all(const float* __restrict__ q, const float* __restrict__ k,
                         const float* __restrict__ v,
                         const float* __restrict__ wq, const float* __restrict__ wk,
                         const float* __restrict__ wv, const float* __restrict__ wo,
                         unsigned short* __restrict__ oq, unsigned short* __restrict__ ok,
                         unsigned short* __restrict__ ov,
                         unsigned short* __restrict__ owq, unsigned short* __restrict__ owk,
                         unsigned short* __restrict__ owv, unsigned short* __restrict__ owo)
{
    const int blk = blockIdx.x;
    const float* in;
    unsigned short* out;
    int i;
    if (blk < 12288) {                       // q/k/v: 4096 blocks each
        const int sel = blk >> 12;           // 0,1,2
        in  = (sel == 0) ? q : (sel == 1) ? k : v;
        out = (sel == 0) ? oq : (sel == 1) ? ok : ov;
        i = ((blk & 4095) << 8) + threadIdx.x;
    } else {                                 // weights: 1024 blocks each
        const int wb = blk - 12288;
        const int sel = wb >> 10;            // 0..3
        in  = (sel == 0) ? wq : (sel == 1) ? wk : (sel == 2) ? wv : wo;
        out = (sel == 0) ? owq : (sel == 1) ? owk : (sel == 2) ? owv : owo;
        i = ((wb & 1023) << 8) + threadIdx.x;
    }
    float4v vv = ((const float4v*)in)[i];
    ushort4v o;
    o.x = f32_bf16(vv.x); o.y = f32_bf16(vv.y);
    o.z = f32_bf16(vv.z); o.w = f32_bf16(vv.w);
    ((ushort4v*)out)[i] = o;
}

// ---------------------------------------------------------------------------
// Batched QKV projection GEMM (R13-exact: 128x128, 4 waves, T2 swizzle).
__global__ __launch_bounds__(256, 2) void gemm_qkv(
    const unsigned short* __restrict__ A0, const unsigned short* __restrict__ A1,
    const unsigned short* __restrict__ A2,
    const unsigned short* __restrict__ W0, const unsigned short* __restrict__ W1,
    const unsigned short* __restrict__ W2,
    const float* __restrict__ bs0, const float* __restrict__ bs1,
    const float* __restrict__ bs2,
    unsigned short* __restrict__ O0, unsigned short* __restrict__ O1,
    unsigned short* __restrict__ O2)
{
    const int z = blockIdx.z;
    const unsigned short* A = (z == 0) ? A0 : (z == 1) ? A1 : A2;
    const unsigned short* W = (z == 0) ? W0 : (z == 1) ? W1 : W2;
    const float* bias        = (z == 0) ? bs0 : (z == 1) ? bs1 : bs2;
    unsigned short* C        = (z == 0) ? O0 : (z == 1) ? O1 : O2;
    const float oscale = (z == 0) ? QSCALE : 1.0f;
    const int N = 1024, K = 1024;

    __shared__ unsigned short As[128 * 64];
    __shared__ unsigned short Bs[128 * 64];
    const int tid  = threadIdx.x;
    const int lane = tid & 63, wave = tid >> 6;
    const int l15 = lane & 15, l4 = lane >> 4;
    const int bm = blockIdx.y * 128, bn = blockIdx.x * 128;
    const int wr = wave >> 1, wc = wave & 1;
    const int swz = l15 & 7;                    // XOR key (8-short units)

    f32x4 acc[4][4];
    #pragma unroll
    for (int i = 0; i < 4; ++i)
        #pragma unroll
        for (int j = 0; j < 4; ++j)
            #pragma unroll
            for (int e = 0; e < 4; ++e) acc[i][j][e] = 0.f;

    const int srow = lane >> 3;                 // row 0..7 within chunk
    const int scol = ((lane & 7) ^ srow) * 8;   // pre-swizzled source col

    for (int k0 = 0; k0 < K; k0 += 64) {
        __syncthreads();
        #pragma unroll
        for (int i = 0; i < 4; ++i) {
            int c = wave * 4 + i;
            int row = c * 8 + srow;
            gload_lds16(A + (size_t)(bm + row) * K + k0 + scol, &As[c * 512]);
            gload_lds16(W + (size_t)(bn + row) * K + k0 + scol, &Bs[c * 512]);
        }
        __syncthreads();
        #pragma unroll
        for (int kk = 0; kk < 2; ++kk) {
            short8 af[4], bf[4];
            const int ko = ((kk * 4 + l4) ^ swz) << 3;   // swizzled col
            #pragma unroll
            for (int i = 0; i < 4; ++i)
                af[i] = *(const short8*)&As[(wr * 64 + i * 16 + l15) * 64 + ko];
            #pragma unroll
            for (int j = 0; j < 4; ++j)
                bf[j] = *(const short8*)&Bs[(wc * 64 + j * 16 + l15) * 64 + ko];
            #pragma unroll
            for (int i = 0; i < 4; ++i)
                #pragma unroll
                for (int j = 0; j < 4; ++j)
                    acc[i][j] = __builtin_amdgcn_mfma_f32_16x16x32_bf16(
                        af[i], bf[j], acc[i][j], 0, 0, 0);
        }
    }

    #pragma unroll
    for (int j = 0; j < 4; ++j) {
        const int col = bn + wc * 64 + j * 16 + l15;
        const float bj = bias[col];
        #pragma unroll
        for (int i = 0; i < 4; ++i) {
            const int row0 = bm + wr * 64 + i * 16 + l4 * 4;
            #pragma unroll
            for (int r = 0; r < 4; ++r) {
                const int row = row0 + r;
                const float v = (acc[i][j][r] + bj) * oscale;
                if (z < 2) {
                    C[(size_t)row * N + col] = f32_bf16(v);
                } else {
                    const int b = row >> 11, t = row & 2047;
                    C[(((size_t)((b << 4) + (col >> 6)) * 64
                        + (col & 63)) << 11) + t] = f32_bf16(v);
                }
            }
        }
    }
}

// ---------------------------------------------------------------------------
// Output-projection GEMM (fp32 out).  R13-exact: 64x128 dbuf + T2 swizzle.
__global__ __launch_bounds__(256, 3) void gemm_out(
    const unsigned short* __restrict__ A,
    const unsigned short* __restrict__ W,
    const float* __restrict__ bias,
    float* __restrict__ C)
{
    const int N = 1024, K = 1024;
    __shared__ unsigned short As[2][64 * 64];
    __shared__ unsigned short Bs[2][128 * 64];
    const int tid  = threadIdx.x;
    const int lane = tid & 63, wave = tid >> 6;
    const int l15 = lane & 15, l4 = lane >> 4;
    const int bm = blockIdx.y * 64, bn = blockIdx.x * 128;
    const int wr = wave >> 1, wc = wave & 1;
    const int swz = l15 & 7;

    f32x4 acc[2][4];
    #pragma unroll
    for (int i = 0; i < 2; ++i)
        #pragma unroll
        for (int j = 0; j < 4; ++j)
            #pragma unroll
            for (int e = 0; e < 4; ++e) acc[i][j][e] = 0.f;

    const int srow = lane >> 3;
    const int scol = ((lane & 7) ^ srow) * 8;

    auto stage = [&](int bf, int k0) {
        #pragma unroll
        for (int i = 0; i < 2; ++i) {
            const int c = wave * 2 + i;
            gload_lds16(A + (size_t)(bm + c * 8 + srow) * K + k0 + scol,
                        &As[bf][c * 512]);
        }
        #pragma unroll
        for (int i = 0; i < 4; ++i) {
            const int c = wave * 4 + i;
            gload_lds16(W + (size_t)(bn + c * 8 + srow) * K + k0 + scol,
                        &Bs[bf][c * 512]);
        }
    };

    stage(0, 0);
    __syncthreads();

    int bufi = 0;
    for (int k0 = 0; k0 < K; k0 += 64) {
        if (k0 + 64 < K) stage(bufi ^ 1, k0 + 64);
        #pragma unroll
        for (int kk = 0; kk < 2; ++kk) {
            short8 af[2], bf[4];
            const int ko = ((kk * 4 + l4) ^ swz) << 3;
            #pragma unroll
            for (int i = 0; i < 2; ++i)
                af[i] = *(const short8*)&As[bufi][(wr * 32 + i * 16 + l15) * 64 + ko];
            #pragma unroll
            for (int j = 0; j < 4; ++j)
                bf[j] = *(const short8*)&Bs[bufi][(wc * 64 + j * 16 + l15) * 64 + ko];
            #pragma unroll
            for (int i = 0; i < 2; ++i)
                #pragma unroll
                for (int j = 0; j < 4; ++j)
                    acc[i][j] = __builtin_amdgcn_mfma_f32_16x16x32_bf16(
                        af[i], bf[j], acc[i][j], 0, 0, 0);
        }
        __syncthreads();
        bufi ^= 1;
    }

    #pragma unroll
    for (int j = 0; j < 4; ++j) {
        const int col = bn + wc * 64 + j * 16 + l15;
        const float bj = bias[col];
        #pragma unroll
        for (int i = 0; i < 2; ++i) {
            const int row0 = bm + wr * 32 + i * 16 + l4 * 4;
            #pragma unroll
            for (int r = 0; r < 4; ++r)
                C[(size_t)(row0 + r) * N + col] = acc[i][j][r] + bj;
        }
    }
}

// ---------------------------------------------------------------------------
// Flash attention, R19-exact (best: 58.1us).  defer-max + branch-local
// shuffles; 8 waves, KVBLK=128 dbuf as two 64-halves, XCD-chunked.
__global__ __launch_bounds__(512, 4) void attn_fwd(
    const unsigned short* __restrict__ qp,
    const unsigned short* __restrict__ kp,
    const unsigned short* __restrict__ vt,
    unsigned short* __restrict__ op)
{
    __shared__ unsigned short Ks[2][128 * 64];  // [buf][kv 0..127][d] swizzled
    __shared__ unsigned short Vs[2][2][64 * 64];// [buf][half][d][kv]  swizzled
    __shared__ unsigned short P[8][16 * 64];    // [wave][q][kv]       swizzled

    const int tid = threadIdx.x;
    const int lane = tid & 63, wave = tid >> 6;  // wave 0..7
    const int l15 = lane & 15, l4 = lane >> 4;
    const int swz = (l15 & 7) << 3;             // XOR mask in short units

    // XCD-chunked block swizzle: 512 blocks, bijective (512%8==0)
    const int flat = blockIdx.x;
    const int swzb = (flat & 7) * 64 + (flat >> 3);
    const int bx = swzb & 15;                   // q-tile index (128 rows)
    const int bh = swzb >> 4;                   // batch*head
    const int b = bh >> 4, h = bh & 15;
    const int q0 = bx * 128 + wave * 16;

    const size_t xbase = (size_t)b * 2048 * 1024 + h * 64;   // qp/kp
    const size_t vbase = (size_t)bh * 64 * 2048;             // vt

    // staging source addressing (pre-swizzled global col, m173 pattern)
    const int sr = lane >> 3;                   // row within 8-row chunk
    const int sc = ((lane & 7) ^ sr) * 8;       // swizzled col (shorts)

    // Q as B-operand frags: col=q(l15), k=d
    short8 bq[2];
    #pragma unroll
    for (int kk = 0; kk < 2; ++kk)
        bq[kk] = *(const short8*)&qp[xbase
            + (size_t)(q0 + l15) * 1024 + kk * 32 + l4 * 8];

    f32x4 acc[4];                   // O^T: [dj]; row=d_local, col=q=l15
    #pragma unroll
    for (int dj = 0; dj < 4; ++dj)
        #pragma unroll
        for (int e = 0; e < 4; ++e) acc[dj][e] = 0.f;

    float m_run = -1e30f, l_part = 0.f;         // l lane-partial (16 kv/lane)

    // staging: K = 16 chunks (2/wave), V = 2 halves x 8 chunks (2/wave total)
    auto stage = [&](int bf, int kv0) {
        #pragma unroll
        for (int i = 0; i < 2; ++i) {
            const int c = wave * 2 + i;
            gload_lds16(kp + xbase + (size_t)(kv0 + c * 8 + sr) * 1024 + sc,
                        &Ks[bf][c * 512]);
        }
        #pragma unroll
        for (int h2 = 0; h2 < 2; ++h2)
            gload_lds16(vt + vbase + (size_t)(wave * 8 + sr) * 2048
                            + kv0 + h2 * 64 + sc,
                        &Vs[bf][h2][wave * 512]);
    };

    // ---- prologue: stage tile 0 into buf 0 ----
    stage(0, 0);
    __syncthreads();

    const int NT = 2048 / 128;
    int buf = 0;
    for (int t = 0; t < NT; ++t) {
        // ---- stage next 128-kv tile into buf^1 ----
        if (t + 1 < NT) stage(buf ^ 1, (t + 1) * 128);

        #pragma unroll
        for (int hh = 0; hh < 2; ++hh) {
            // ---- S^T = K Q^T for this 64-kv half ----
            f32x4 st[4];            // kv = hh*64 + j*16 + l4*4 + r ; q = l15
            {
                short8 ak[4];
                #pragma unroll
                for (int j = 0; j < 4; ++j)
                    ak[j] = *(const short8*)&Ks[buf][(hh * 64 + j * 16 + l15) * 64
                                                     + ((l4 << 3) ^ swz)];
                const f32x4 z4 = {0.f, 0.f, 0.f, 0.f};
                #pragma unroll
                for (int j = 0; j < 4; ++j)
                    st[j] = __builtin_amdgcn_mfma_f32_16x16x32_bf16(
                        ak[j], bq[0], z4, 0, 0, 0);
                #pragma unroll
                for (int j = 0; j < 4; ++j)
                    ak[j] = *(const short8*)&Ks[buf][(hh * 64 + j * 16 + l15) * 64
                                                     + (((4 + l4) << 3) ^ swz)];
                #pragma unroll
                for (int j = 0; j < 4; ++j)
                    st[j] = __builtin_amdgcn_mfma_f32_16x16x32_bf16(
                        ak[j], bq[1], st[j], 0, 0, 0);
            }

            // ---- prefetch V frags for this half ----
            short8 av[2][4];        // [kvc][dj]
            #pragma unroll
            for (int kvc = 0; kvc < 2; ++kvc)
                #pragma unroll
                for (int dj = 0; dj < 4; ++dj)
                    av[kvc][dj] = *(const short8*)&Vs[buf][hh]
                        [(dj * 16 + l15) * 64 + (((kvc * 4 + l4) << 3) ^ swz)];

            // ---- softmax (exp2 domain), defer-max, branch-local shuffles ----
            {
                float tm[4];
                #pragma unroll
                for (int j = 0; j < 4; ++j)
                    tm[j] = fmaxf(fmaxf(st[j][0], st[j][1]),
                                  fmaxf(st[j][2], st[j][3]));
                const float mxl = fmaxf(fmaxf(tm[0], tm[1]),
                                        fmaxf(tm[2], tm[3]));   // lane-local
                // row max <= m_run+8  iff  all 4 lanes' local maxima pass
                if (!__all(mxl - m_run <= 8.0f)) {
                    float mx = fmaxf(mxl, __shfl_xor(mxl, 16));
                    mx = fmaxf(mx, __shfl_xor(mx, 32));
                    const float mnew = fmaxf(m_run, mx);
                    const float corr = exp2_fast(m_run - mnew);
                    m_run = mnew;
                    l_part *= corr;
                    #pragma unroll
                    for (int dj = 0; dj < 4; ++dj) acc[dj] *= corr;
                }
                float ts[4];
                #pragma unroll
                for (int j = 0; j < 4; ++j) {
                    float p0 = exp2_fast(st[j][0] - m_run);
                    float p1 = exp2_fast(st[j][1] - m_run);
                    float p2 = exp2_fast(st[j][2] - m_run);
                    float p3 = exp2_fast(st[j][3] - m_run);
                    st[j][0] = p0; st[j][1] = p1;
                    st[j][2] = p2; st[j][3] = p3;
                    ts[j] = (p0 + p1) + (p2 + p3);
                }
                l_part += (ts[0] + ts[1]) + (ts[2] + ts[3]);
            }

            // ---- P^T -> swizzled per-wave LDS (b64 writes) ----
            #pragma unroll
            for (int j = 0; j < 4; ++j) {
                uint2v w;
                w.x = cvt_pk_bf16(st[j][0], st[j][1]);
                w.y = cvt_pk_bf16(st[j][2], st[j][3]);
                *(uint2v*)&P[wave][l15 * 64 + ((j * 16 + l4 * 4) ^ swz)] = w;
            }

            // ---- O^T += V^T P^T ----
            #pragma unroll
            for (int kvc = 0; kvc < 2; ++kvc) {
                short8 pb = *(const short8*)&P[wave][l15 * 64
                                                + (((kvc * 4 + l4) << 3) ^ swz)];
                #pragma unroll
                for (int dj = 0; dj < 4; ++dj)
                    acc[dj] = __builtin_amdgcn_mfma_f32_16x16x32_bf16(
                        av[kvc][dj], pb, acc[dj], 0, 0, 0);
            }
        }

        __syncthreads();            // drains vmcnt (staging done) + LDS reads
        buf ^= 1;
    }

    // ---- epilogue: reduce lane-partial l, divide, 8B vector stores ----
    {
        float l = l_part;
        l += __shfl_xor(l, 16);
        l += __shfl_xor(l, 32);
        const float inv = 1.0f / l;
        const int t = q0 + l15;
        #pragma unroll
        for (int dj = 0; dj < 4; ++dj) {
            uint2v w;
            w.x = cvt_pk_bf16(acc[dj][0] * inv, acc[dj][1] * inv);
            w.y = cvt_pk_bf16(acc[dj][2] * inv, acc[dj][3] * inv);
            *(uint2v*)&op[((size_t)(b * 2048 + t)) * 1024
                          + h * 64 + dj * 16 + l4 * 4] = w;
        }
    }
}

// ---------------------------------------------------------------------------
extern "C" void kernel_launch(void* const* d_in, const int* in_sizes, int n_in,
                              void* d_out, int out_size, void* d_ws, size_t ws_size,
                              hipStream_t stream)
{
    const float* q  = (const float*)d_in[0];
    const float* k  = (const float*)d_in[1];
    const float* v  = (const float*)d_in[2];
    const float* wq = (const float*)d_in[3];
    const float* bq = (const float*)d_in[4];
    const float* wk = (const float*)d_in[5];
    const float* bk = (const float*)d_in[6];
    const float* wv = (const float*)d_in[7];
    const float* bv = (const float*)d_in[8];
    const float* wo = (const float*)d_in[9];
    const float* bo = (const float*)d_in[10];
    float* out = (float*)d_out;

    const int M = 4096, N = 1024;
    unsigned char* ws = (unsigned char*)d_ws;
    const size_t SX = (size_t)M * 1024 * 2;     // 8 MB
    const size_t SW = (size_t)N * 1024 * 2;     // 2 MB
    unsigned short* xq  = (unsigned short*)(ws);
    unsigned short* xk  = (unsigned short*)(ws + SX);
    unsigned short* xv  = (unsigned short*)(ws + 2 * SX);
    unsigned short* wqb = (unsigned short*)(ws + 3 * SX);
    unsigned short* wkb = (unsigned short*)(ws + 3 * SX + SW);
    unsigned short* wvb = (unsigned short*)(ws + 3 * SX + 2 * SW);
    unsigned short* wob = (unsigned short*)(ws + 3 * SX + 3 * SW);
    unsigned short* qp  = (unsigned short*)(ws + 3 * SX + 4 * SW);
    unsigned short* kp  = qp + (size_t)M * N;
    unsigned short* vt  = kp + (size_t)M * N;
    unsigned short* opb = vt + (size_t)M * N;

    pack_all<<<dim3(16384), 256, 0, stream>>>(q, k, v, wq, wk, wv, wo,
                                              xq, xk, xv, wqb, wkb, wvb, wob);

    gemm_qkv<<<dim3(8, 32, 3), 256, 0, stream>>>(xq, xk, xv, wqb, wkb, wvb,
                                                 bq, bk, bv, qp, kp, vt);

    attn_fwd<<<dim3(512), 512, 0, stream>>>(qp, kp, vt, opb);

    gemm_out<<<dim3(8, 64), 256, 0, stream>>>(opb, wob, bo, out);
}